// Round 4
// baseline (314.041 us; speedup 1.0000x reference)
//
#include <hip/hip_runtime.h>
#include <cstdint>

#define BH 48
#define SEQ 4096
#define DIM 64
#define SEG 64
#define NCHUNK 8
#define CHUNK 512
#define PAD 68
#define BSTR 72   // bf16 row stride in ushorts (144 B = 16B-aligned, lane bank offset 4 -> 2-way max)

static constexpr float INV_SCALE = 0.35355339059327379f; // 1/sqrt(sqrt(64))

// workspace float offsets
#define OFF_QL   0u        // 48*4096
#define OFF_KL   196608u   // 48*4096
#define OFF_K2   393216u   // 48*4096
#define OFF_W    589824u   // 48*4096
#define OFF_P    786432u   // 48*4096
#define OFF_MNUM 983040u   // 48*8*4096
#define OFF_MDEN 2555904u  // 48*8*64
#define OFF_CMAX 2580480u  // 48
#define OFF_RMAX 2580528u  // 48  (total 2580576 floats ~ 10.3 MB)

typedef __attribute__((ext_vector_type(8))) short short8;
typedef __attribute__((ext_vector_type(4))) float f32x4;
#define MFMA16(a,b,c) __builtin_amdgcn_mfma_f32_16x16x32_bf16(a,b,c,0,0,0)

__device__ __forceinline__ float4 ld4(const float* p){ return *reinterpret_cast<const float4*>(p); }
__device__ __forceinline__ void st4(float* p, float4 v){ *reinterpret_cast<float4*>(p) = v; }

// bf16 high part (round-to-nearest-even) and low residual part
__device__ __forceinline__ unsigned short bfh_(float x){
  unsigned u = __float_as_uint(x);
  return (unsigned short)((u + 0x7fffu + ((u>>16)&1u)) >> 16);
}
__device__ __forceinline__ unsigned short bfl_(float x, unsigned short h){
  float r = x - __uint_as_float(((unsigned)h)<<16);
  return (unsigned short)(__float_as_uint(r) >> 16);   // truncate; residual-of-residual ~2^-17
}
__device__ __forceinline__ void split4(float4 v, uint2& hi, uint2& lo){
  unsigned short h0=bfh_(v.x), h1=bfh_(v.y), h2=bfh_(v.z), h3=bfh_(v.w);
  unsigned short l0=bfl_(v.x,h0), l1=bfl_(v.y,h1), l2=bfl_(v.z,h2), l3=bfl_(v.w,h3);
  hi = make_uint2((unsigned)h0 | ((unsigned)h1<<16), (unsigned)h2 | ((unsigned)h3<<16));
  lo = make_uint2((unsigned)l0 | ((unsigned)l1<<16), (unsigned)l2 | ((unsigned)l3<<16));
}

// C[4][4] += A[i0..i0+3][:] * B[:][j0..j0+3], 64-deep, LDS operands (pad=68 keeps 16B align)
__device__ __forceinline__ void mm_tile(float c[4][4], const float (*A)[PAD], const float (*B)[PAD], int i0, int j0){
  #pragma unroll 4
  for(int k=0;k<64;k+=4){
    float4 a4[4];
    #pragma unroll
    for(int r=0;r<4;r++) a4[r] = ld4(&A[i0+r][k]);
    #pragma unroll
    for(int kk=0;kk<4;kk++){
      float4 bv = ld4(&B[k+kk][j0]);
      #pragma unroll
      for(int r=0;r<4;r++){
        float a = ((const float*)&a4[r])[kk];
        c[r][0] += a*bv.x; c[r][1] += a*bv.y; c[r][2] += a*bv.z; c[r][3] += a*bv.w;
      }
    }
  }
}

// C[4][4] += A * (dg*I - B)   (Newton-Schulz steps)
__device__ __forceinline__ void mm_tile_diag(float c[4][4], const float (*A)[PAD], const float (*B)[PAD], int i0, int j0, float dg){
  #pragma unroll 4
  for(int k=0;k<64;k+=4){
    float4 a4[4];
    #pragma unroll
    for(int r=0;r<4;r++) a4[r] = ld4(&A[i0+r][k]);
    #pragma unroll
    for(int kk=0;kk<4;kk++){
      float4 bv = ld4(&B[k+kk][j0]);
      float b0=-bv.x, b1=-bv.y, b2=-bv.z, b3=-bv.w;
      int dd = k+kk-j0;
      if(dd==0) b0+=dg; else if(dd==1) b1+=dg; else if(dd==2) b2+=dg; else if(dd==3) b3+=dg;
      #pragma unroll
      for(int r=0;r<4;r++){
        float a = ((const float*)&a4[r])[kk];
        c[r][0]+=a*b0; c[r][1]+=a*b1; c[r][2]+=a*b2; c[r][3]+=a*b3;
      }
    }
  }
}

// ---------------- 1. landmark pooling (reads Q,K once; writes scaled QL,KL) ----------------
__global__ __launch_bounds__(256) void pool_kernel(const float* __restrict__ Qg, const float* __restrict__ Kg, float* __restrict__ ws){
  int bx = blockIdx.x;              // 48 heads * 2 tensors * 16 landmark-groups = 1536
  int head = bx >> 5;
  int rest = bx & 31;
  int tensor = rest >> 4;           // 0:Q 1:K
  int l0 = (rest & 15) * 4;
  int t = threadIdx.x;
  int ll = t >> 6;                  // wave id -> local landmark
  int lane = t & 63;
  int d4 = (lane & 15) * 4;
  int rq = lane >> 4;               // row phase 0..3
  const float* src = tensor ? Kg : Qg;
  float* dst = ws + (tensor ? OFF_KL : OFF_QL);
  int l = l0 + ll;
  const float* base = src + ((size_t)head*SEQ + (size_t)l*SEG)*DIM + d4;
  float sx=0.f, sy=0.f, sz=0.f, sw=0.f;
  #pragma unroll 4
  for(int r=rq; r<SEG; r+=4){
    float4 v = ld4(base + (size_t)r*DIM);
    sx+=v.x; sy+=v.y; sz+=v.z; sw+=v.w;
  }
  sx += __shfl_xor(sx,16); sy += __shfl_xor(sy,16); sz += __shfl_xor(sz,16); sw += __shfl_xor(sw,16);
  sx += __shfl_xor(sx,32); sy += __shfl_xor(sy,32); sz += __shfl_xor(sz,32); sw += __shfl_xor(sw,32);
  if(rq==0){
    const float sc = INV_SCALE / 64.0f;
    float4 o; o.x=sx*sc; o.y=sy*sc; o.z=sz*sc; o.w=sw*sc;
    st4(dst + ((size_t)head*64 + l)*DIM + d4, o);
  }
}

// ---------------- 2. kernel_2 softmax + per-head L1 row/col max ----------------
__global__ __launch_bounds__(256) void k2_kernel(float* __restrict__ ws){
  __shared__ float sQ[64][65];
  __shared__ float sK[64][65];
  __shared__ float sE[64][65];
  __shared__ float red[128];
  int h = blockIdx.x, t = threadIdx.x;
  const float* QL = ws + OFF_QL + (size_t)h*4096;
  const float* KL = ws + OFF_KL + (size_t)h*4096;
  for(int i=t;i<4096;i+=256){ sQ[i>>6][i&63]=QL[i]; sK[i>>6][i&63]=KL[i]; }
  __syncthreads();
  int i = t>>2, q = t&3;
  float l[16];
  #pragma unroll
  for(int jj=0;jj<16;jj++){
    int j = q*16+jj;
    float s=0.f;
    for(int d=0;d<64;d++) s += sQ[i][d]*sK[j][d];
    l[jj]=s;
  }
  float mx = l[0];
  #pragma unroll
  for(int jj=1;jj<16;jj++) mx = fmaxf(mx,l[jj]);
  mx = fmaxf(mx, __shfl_xor(mx,1));
  mx = fmaxf(mx, __shfl_xor(mx,2));
  float sum=0.f;
  #pragma unroll
  for(int jj=0;jj<16;jj++){ l[jj]=__expf(l[jj]-mx); sum+=l[jj]; }
  sum += __shfl_xor(sum,1);
  sum += __shfl_xor(sum,2);
  float inv = 1.0f/sum;
  #pragma unroll
  for(int jj=0;jj<16;jj++) sE[i][q*16+jj] = l[jj]*inv;
  __syncthreads();
  float* K2 = ws + OFF_K2 + (size_t)h*4096;
  for(int idx=t; idx<4096; idx+=256) K2[idx] = sE[idx>>6][idx&63];
  if(t<64){
    float cs=0.f, rs=0.f;
    for(int r=0;r<64;r++){ cs += sE[r][t]; rs += sE[t][r]; }
    red[t]=cs; red[64+t]=rs;
  }
  __syncthreads();
  if(t==0){
    float cm=0.f, rm=0.f;
    for(int j=0;j<64;j++){ cm=fmaxf(cm,red[j]); rm=fmaxf(rm,red[64+j]); }
    ws[OFF_CMAX+h]=cm; ws[OFF_RMAX+h]=rm;
  }
}

// ---------------- 3. fused: Newton-Schulz (blocks 0..47, fp32 VALU) || kernel_3@V partials (MFMA bf16x3) ----------------
__global__ __launch_bounds__(256) void fused_kernel(const float* __restrict__ Kg, const float* __restrict__ Vg, float* __restrict__ ws){
  __shared__ __align__(16) unsigned char smem[74752];
  __shared__ float sscale;
  int bid = blockIdx.x, t = threadIdx.x;
  if(bid < BH){
    // ---- Newton-Schulz pseudo-inverse of kernel_2, head=bid (unchanged fp32 path) ----
    int i0 = (t>>4)*4, j0 = (t&15)*4;
    int h = bid;
    float (*Km)[PAD]=(float(*)[PAD])(smem);
    float (*Vm)[PAD]=(float(*)[PAD])(smem+17408);
    float (*B1)[PAD]=(float(*)[PAD])(smem+34816);
    float (*B2)[PAD]=(float(*)[PAD])(smem+52224);
    const float* K2 = ws + OFF_K2 + (size_t)h*4096;
    for(int i=t;i<4096;i+=256) Km[i>>6][i&63]=K2[i];
    if(t==0){
      float cm=0.f, rm=0.f;
      for(int j=0;j<BH;j++){ cm=fmaxf(cm,ws[OFF_CMAX+j]); rm=fmaxf(rm,ws[OFF_RMAX+j]); }
      sscale = 1.0f/(cm*rm);   // global (all heads) scale, matches reference
    }
    __syncthreads();
    float scale = sscale;
    for(int i=t;i<4096;i+=256) Vm[i>>6][i&63] = scale * Km[i&63][i>>6];  // scale * Km^T
    __syncthreads();
    for(int it=0; it<6; it++){
      { // B1 = Km @ Vm   (KV)
        float c[4][4]={};
        mm_tile(c,Km,Vm,i0,j0);
        #pragma unroll
        for(int r=0;r<4;r++){ float4 o; o.x=c[r][0];o.y=c[r][1];o.z=c[r][2];o.w=c[r][3]; st4(&B1[i0+r][j0],o); }
        __syncthreads();
      }
      { // B2 = KV @ (7I - KV)
        float c[4][4]={};
        mm_tile_diag(c,B1,B1,i0,j0,7.0f);
        #pragma unroll
        for(int r=0;r<4;r++){ float4 o; o.x=c[r][0];o.y=c[r][1];o.z=c[r][2];o.w=c[r][3]; st4(&B2[i0+r][j0],o); }
        __syncthreads();
      }
      { // B1 = KV @ (15I - B2)   (in-place on B1: compute -> barrier -> write)
        float c[4][4]={};
        mm_tile_diag(c,B1,B2,i0,j0,15.0f);
        __syncthreads();
        #pragma unroll
        for(int r=0;r<4;r++){ float4 o; o.x=c[r][0];o.y=c[r][1];o.z=c[r][2];o.w=c[r][3]; st4(&B1[i0+r][j0],o); }
        __syncthreads();
      }
      { // Vm = 0.25 * Vm @ (13I - B1)
        float c[4][4]={};
        mm_tile_diag(c,Vm,B1,i0,j0,13.0f);
        __syncthreads();
        #pragma unroll
        for(int r=0;r<4;r++){ float4 o; o.x=0.25f*c[r][0];o.y=0.25f*c[r][1];o.z=0.25f*c[r][2];o.w=0.25f*c[r][3]; st4(&Vm[i0+r][j0],o); }
        __syncthreads();
      }
    }
    float* W = ws + OFF_W + (size_t)h*4096;
    for(int i=t;i<4096;i+=256) W[i] = Vm[i>>6][i&63];
  } else {
    // ---- kernel_3 @ V partial via MFMA bf16x3: block = (head, 512-key chunk) ----
    int b = bid - BH;
    int h = b >> 3, ch = b & 7;
    unsigned short* QLh=(unsigned short*)smem;   // each array 64*BSTR ushorts = 9216 B
    unsigned short* QLl=QLh+4608;
    unsigned short* Kth=QLh+9216;
    unsigned short* Ktl=QLh+13824;
    unsigned short* VTh=QLh+18432;
    unsigned short* VTl=QLh+23040;
    unsigned short* PTh=QLh+27648;
    unsigned short* PTl=QLh+32256;
    float* sden=(float*)(smem+73728);            // [4][64]
    const int lane=t&63, w=t>>6, ln=lane&15, g=lane>>4;
    const int rr=t>>4, c4=(t&15)*4;
    const float* QL = ws + OFF_QL + (size_t)h*4096;
    // stage QL (hi/lo bf16, m-major rows, k=d contiguous)
    #pragma unroll
    for(int gg=0;gg<4;gg++){
      int m=rr+16*gg;
      float4 v=ld4(QL+m*64+c4);
      uint2 hi,lo; split4(v,hi,lo);
      *reinterpret_cast<uint2*>(QLh+m*BSTR+c4)=hi;
      *reinterpret_cast<uint2*>(QLl+m*BSTR+c4)=lo;
    }
    const size_t kbase=((size_t)h*SEQ+(size_t)ch*CHUNK)*DIM;
    // prologue: prefetch tile 0 into registers
    float4 kr[4],vr[4];
    #pragma unroll
    for(int gg=0;gg<4;gg++){
      size_t off=kbase+(size_t)(rr+16*gg)*DIM+c4;
      kr[gg]=ld4(Kg+off); vr[gg]=ld4(Vg+off);
    }
    f32x4 acc[4];
    #pragma unroll
    for(int ni=0;ni<4;ni++) acc[ni]=(f32x4){0.f,0.f,0.f,0.f};
    float den_acc[4]={0.f,0.f,0.f,0.f};
    for(int tile=0;tile<8;tile++){
      __syncthreads();   // prev tile's LDS reads done (also covers QL staging on first pass)
      // stage K (scaled, s'-major) and V^T (d-major, s'-contiguous, XOR-swizzled scatter)
      #pragma unroll
      for(int gg=0;gg<4;gg++){
        int r=rr+16*gg;
        float4 kv=kr[gg];
        kv.x*=INV_SCALE; kv.y*=INV_SCALE; kv.z*=INV_SCALE; kv.w*=INV_SCALE;
        uint2 hi,lo; split4(kv,hi,lo);
        *reinterpret_cast<uint2*>(Kth+r*BSTR+c4)=hi;
        *reinterpret_cast<uint2*>(Ktl+r*BSTR+c4)=lo;
        float fv[4]={vr[gg].x,vr[gg].y,vr[gg].z,vr[gg].w};
        #pragma unroll
        for(int e=0;e<4;e++){
          int d=c4+e;
          unsigned short hv=bfh_(fv[e]);
          unsigned short lv=bfl_(fv[e],hv);
          int sp = r ^ (((d>>2)&7)<<3);   // swizzle s' bits 3..5 by d bits 2..4 (store-side)
          VTh[d*BSTR+sp]=hv; VTl[d*BSTR+sp]=lv;
        }
      }
      // issue next tile's global loads (latency hidden under the MFMA phases)
      if(tile<7){
        #pragma unroll
        for(int gg=0;gg<4;gg++){
          size_t off=kbase+(size_t)((tile+1)*64+rr+16*gg)*DIM+c4;
          kr[gg]=ld4(Kg+off); vr[gg]=ld4(Vg+off);
        }
      }
      __syncthreads();
      // ---- logits: D[s'][m] = K_scaled . QL ; wave w owns s' rows 16w..16w+15 ----
      short8 kah[2],kal[2];
      #pragma unroll
      for(int kh=0;kh<2;kh++){
        int ab=(16*w+ln)*BSTR+32*kh+8*g;
        kah[kh]=*reinterpret_cast<const short8*>(Kth+ab);
        kal[kh]=*reinterpret_cast<const short8*>(Ktl+ab);
      }
      #pragma unroll
      for(int ni=0;ni<4;ni++){
        f32x4 dl=(f32x4){0.f,0.f,0.f,0.f};
        #pragma unroll
        for(int kh=0;kh<2;kh++){
          int bb=(16*ni+ln)*BSTR+32*kh+8*g;
          short8 bh=*reinterpret_cast<const short8*>(QLh+bb);
          short8 bl=*reinterpret_cast<const short8*>(QLl+bb);
          dl=MFMA16(kah[kh],bh,dl);
          dl=MFMA16(kah[kh],bl,dl);
          dl=MFMA16(kal[kh],bh,dl);
        }
        // P = exp(logits); D layout: row s' = 16w + 4g + reg, col m = 16ni + ln
        float p0=__expf(dl[0]), p1=__expf(dl[1]), p2=__expf(dl[2]), p3=__expf(dl[3]);
        den_acc[ni]+=p0+p1+p2+p3;
        unsigned short h0=bfh_(p0),h1=bfh_(p1),h2=bfh_(p2),h3=bfh_(p3);
        unsigned short l0=bfl_(p0,h0),l1=bfl_(p1,h1),l2=bfl_(p2,h2),l3=bfl_(p3,h3);
        int pb=(16*ni+ln)*BSTR+16*w+4*g;   // PT[m][s'] s'-contiguous
        *reinterpret_cast<uint2*>(PTh+pb)=make_uint2((unsigned)h0|((unsigned)h1<<16),(unsigned)h2|((unsigned)h3<<16));
        *reinterpret_cast<uint2*>(PTl+pb)=make_uint2((unsigned)l0|((unsigned)l1<<16),(unsigned)l2|((unsigned)l3<<16));
      }
      __syncthreads();
      // ---- PV: acc[m][d] += P^T . V ; wave w owns m rows 16w..16w+15 ----
      short8 pah[2],pal[2];
      #pragma unroll
      for(int kh=0;kh<2;kh++){
        int pb=(16*w+ln)*BSTR+32*kh+8*g;
        pah[kh]=*reinterpret_cast<const short8*>(PTh+pb);
        pal[kh]=*reinterpret_cast<const short8*>(PTl+pb);
      }
      #pragma unroll
      for(int ni=0;ni<4;ni++){
        int row=16*ni+ln;                 // row = d
        int swz=((row>>2)&7)<<3;
        #pragma unroll
        for(int kh=0;kh<2;kh++){
          int vb=row*BSTR+((32*kh+8*g)^swz);   // compensate store-side swizzle
          short8 vh=*reinterpret_cast<const short8*>(VTh+vb);
          short8 vl=*reinterpret_cast<const short8*>(VTl+vb);
          acc[ni]=MFMA16(pah[kh],vh,acc[ni]);
          acc[ni]=MFMA16(pah[kh],vl,acc[ni]);
          acc[ni]=MFMA16(pal[kh],vh,acc[ni]);
        }
      }
    }
    // epilogue: MNUM partials (D layout: row m = 16w+4g+r, col d = 16ni+ln)
    float* num = ws + OFF_MNUM + (size_t)b*4096;
    #pragma unroll
    for(int ni=0;ni<4;ni++){
      #pragma unroll
      for(int r=0;r<4;r++) num[(16*w+4*g+r)*64+16*ni+ln]=acc[ni][r];
      den_acc[ni]+=__shfl_xor(den_acc[ni],16);
      den_acc[ni]+=__shfl_xor(den_acc[ni],32);
    }
    if(lane<16){
      #pragma unroll
      for(int ni=0;ni<4;ni++) sden[w*64+16*ni+lane]=den_acc[ni];
    }
    __syncthreads();
    if(t<64) ws[OFF_MDEN+(size_t)b*64+t]=sden[t]+sden[64+t]+sden[128+t]+sden[192+t];
  }
}

// ---------------- 4. combine partials -> M, then P = W @ M ----------------
__global__ __launch_bounds__(256) void combine_kernel(float* __restrict__ ws){
  __shared__ float sW[64][PAD];
  __shared__ float sM[64][PAD];
  __shared__ float sden[64];
  int h=blockIdx.x, t=threadIdx.x;
  if(t<64){
    float s=0.f;
    for(int c=0;c<NCHUNK;c++) s += ws[OFF_MDEN + ((size_t)h*NCHUNK+c)*64 + t];
    sden[t]=1.0f/s;
  }
  for(int i=t;i<4096;i+=256) sW[i>>6][i&63] = ws[OFF_W + (size_t)h*4096 + i];
  __syncthreads();
  for(int i=t;i<1024;i+=256){
    int m=i>>4, d4=(i&15)*4;
    float sx=0.f,sy=0.f,sz=0.f,sw2=0.f;
    for(int c=0;c<NCHUNK;c++){
      float4 v = ld4(ws + OFF_MNUM + ((size_t)h*NCHUNK+c)*4096 + m*64 + d4);
      sx+=v.x; sy+=v.y; sz+=v.z; sw2+=v.w;
    }
    float iv = sden[m];
    float4 o; o.x=sx*iv; o.y=sy*iv; o.z=sz*iv; o.w=sw2*iv;
    st4(&sM[m][d4], o);
  }
  __syncthreads();
  int i0=(t>>4)*4, j0=(t&15)*4;
  float c[4][4]={};
  mm_tile(c, sW, sM, i0, j0);
  float* P = ws + OFF_P + (size_t)h*4096;
  #pragma unroll
  for(int r=0;r<4;r++){
    float4 o; o.x=c[r][0]; o.y=c[r][1]; o.z=c[r][2]; o.w=c[r][3];
    st4(P + (i0+r)*64 + j0, o);
  }
}

// ---------------- 5. X = rowsoftmax(Q . KL^T) @ P ----------------
__global__ __launch_bounds__(256) void final_kernel(const float* __restrict__ Qg, float* __restrict__ out, const float* __restrict__ ws){
  __shared__ float sKLT[64][PAD];
  __shared__ float sP[64][PAD];
  __shared__ float sQE[64][PAD];
  int bid=blockIdx.x, t=threadIdx.x;
  int h=bid>>6, s0=(bid&63)*64;
  const float* KL = ws + OFF_KL + (size_t)h*4096;
  const float* P  = ws + OFF_P  + (size_t)h*4096;
  const float* Qb = Qg + ((size_t)h*SEQ + (size_t)s0)*DIM;
  for(int i=t;i<1024;i+=256){
    int m=i>>4, d4=(i&15)*4;
    float4 v = ld4(KL + m*64 + d4);
    sKLT[d4+0][m]=v.x; sKLT[d4+1][m]=v.y; sKLT[d4+2][m]=v.z; sKLT[d4+3][m]=v.w;
    st4(&sP[m][d4], ld4(P + m*64 + d4));
    float4 q = ld4(Qb + (size_t)m*DIM + d4);
    q.x*=INV_SCALE; q.y*=INV_SCALE; q.z*=INV_SCALE; q.w*=INV_SCALE;
    st4(&sQE[m][d4], q);
  }
  __syncthreads();
  int i0=(t>>4)*4, j0=(t&15)*4;
  float l[4][4]={};
  mm_tile(l, sQE, sKLT, i0, j0);
  float e[4][4]; float rs[4];
  #pragma unroll
  for(int r=0;r<4;r++){
    float s=0.f;
    #pragma unroll
    for(int cc=0;cc<4;cc++){ e[r][cc]=__expf(l[r][cc]); s+=e[r][cc]; }
    rs[r]=s;
  }
  #pragma unroll
  for(int r=0;r<4;r++){
    rs[r]+=__shfl_xor(rs[r],1);
    rs[r]+=__shfl_xor(rs[r],2);
    rs[r]+=__shfl_xor(rs[r],4);
    rs[r]+=__shfl_xor(rs[r],8);
  }
  __syncthreads();    // all reads of sQE (as Q) done -> overwrite with E
  #pragma unroll
  for(int r=0;r<4;r++){ float4 o; o.x=e[r][0]; o.y=e[r][1]; o.z=e[r][2]; o.w=e[r][3]; st4(&sQE[i0+r][j0], o); }
  __syncthreads();
  float c[4][4]={};
  mm_tile(c, sQE, sP, i0, j0);
  #pragma unroll
  for(int r=0;r<4;r++){
    float iv = 1.0f/rs[r];
    float4 o; o.x=c[r][0]*iv; o.y=c[r][1]*iv; o.z=c[r][2]*iv; o.w=c[r][3]*iv;
    st4(out + ((size_t)h*SEQ + (size_t)(s0+i0+r))*DIM + j0, o);
  }
}

extern "C" void kernel_launch(void* const* d_in, const int* in_sizes, int n_in,
                              void* d_out, int out_size, void* d_ws, size_t ws_size,
                              hipStream_t stream) {
  const float* Q = (const float*)d_in[0];
  const float* K = (const float*)d_in[1];
  const float* V = (const float*)d_in[2];
  float* out = (float*)d_out;
  float* ws  = (float*)d_ws;

  pool_kernel   <<<BH*32, 256, 0, stream>>>(Q, K, ws);
  k2_kernel     <<<BH,    256, 0, stream>>>(ws);
  fused_kernel  <<<BH + BH*NCHUNK, 256, 0, stream>>>(K, V, ws);
  combine_kernel<<<BH,    256, 0, stream>>>(ws);
  final_kernel  <<<BH*64, 256, 0, stream>>>(Q, out, ws);
}

// Round 5
// 269.684 us; speedup vs baseline: 1.1645x; 1.1645x over previous
//
#include <hip/hip_runtime.h>
#include <cstdint>

#define BH 48
#define SEQ 4096
#define DIM 64
#define SEG 64
#define NCHUNK 8
#define CHUNK 512
#define PAD 68
#define BSTR 72   // bf16 row stride in ushorts (144 B = 16B-aligned)

static constexpr float INV_SCALE = 0.35355339059327379f; // 1/sqrt(sqrt(64))

// workspace float offsets
#define OFF_QL   0u        // 48*4096
#define OFF_KL   196608u   // 48*4096
#define OFF_K2   393216u   // 48*4096
#define OFF_W    589824u   // 48*4096
#define OFF_P    786432u   // 48*4096
#define OFF_MNUM 983040u   // 48*8*4096
#define OFF_MDEN 2555904u  // 48*8*64
#define OFF_CMAX 2580480u  // 48
#define OFF_RMAX 2580528u  // 48  (total 2580576 floats ~ 10.3 MB)

typedef __attribute__((ext_vector_type(8))) short short8;
typedef __attribute__((ext_vector_type(4))) float f32x4;
#define MFMA16(a,b,c) __builtin_amdgcn_mfma_f32_16x16x32_bf16(a,b,c,0,0,0)

__device__ __forceinline__ float4 ld4(const float* p){ return *reinterpret_cast<const float4*>(p); }
__device__ __forceinline__ void st4(float* p, float4 v){ *reinterpret_cast<float4*>(p) = v; }

// bf16 high part (round-to-nearest-even) and low residual part
__device__ __forceinline__ unsigned short bfh_(float x){
  unsigned u = __float_as_uint(x);
  return (unsigned short)((u + 0x7fffu + ((u>>16)&1u)) >> 16);
}
__device__ __forceinline__ unsigned short bfl_(float x, unsigned short h){
  float r = x - __uint_as_float(((unsigned)h)<<16);
  return (unsigned short)(__float_as_uint(r) >> 16);   // truncate; residual-of-residual ~2^-17
}
__device__ __forceinline__ void split4(float4 v, uint2& hi, uint2& lo){
  unsigned short h0=bfh_(v.x), h1=bfh_(v.y), h2=bfh_(v.z), h3=bfh_(v.w);
  unsigned short l0=bfl_(v.x,h0), l1=bfl_(v.y,h1), l2=bfl_(v.z,h2), l3=bfl_(v.w,h3);
  hi = make_uint2((unsigned)h0 | ((unsigned)h1<<16), (unsigned)h2 | ((unsigned)h3<<16));
  lo = make_uint2((unsigned)l0 | ((unsigned)l1<<16), (unsigned)l2 | ((unsigned)l3<<16));
}
__device__ __forceinline__ short8 mk8(uint2 a, uint2 b){
  union { short8 s; uint4 u; } x; x.u = make_uint4(a.x,a.y,b.x,b.y); return x.s;
}

// C[4][4] += A[i0..i0+3][:] * B[:][j0..j0+3], 64-deep, LDS operands (pad=68 keeps 16B align)
__device__ __forceinline__ void mm_tile(float c[4][4], const float (*A)[PAD], const float (*B)[PAD], int i0, int j0){
  #pragma unroll 4
  for(int k=0;k<64;k+=4){
    float4 a4[4];
    #pragma unroll
    for(int r=0;r<4;r++) a4[r] = ld4(&A[i0+r][k]);
    #pragma unroll
    for(int kk=0;kk<4;kk++){
      float4 bv = ld4(&B[k+kk][j0]);
      #pragma unroll
      for(int r=0;r<4;r++){
        float a = ((const float*)&a4[r])[kk];
        c[r][0] += a*bv.x; c[r][1] += a*bv.y; c[r][2] += a*bv.z; c[r][3] += a*bv.w;
      }
    }
  }
}

// same, but A rows come straight from global (row-major, stride 64) — L2-resident broadcast reads
__device__ __forceinline__ void mm_tile_gA(float c[4][4], const float* __restrict__ gA, const float (*B)[PAD], int i0, int j0){
  #pragma unroll 4
  for(int k=0;k<64;k+=4){
    float4 a4[4];
    #pragma unroll
    for(int r=0;r<4;r++) a4[r] = ld4(gA + (i0+r)*64 + k);
    #pragma unroll
    for(int kk=0;kk<4;kk++){
      float4 bv = ld4(&B[k+kk][j0]);
      #pragma unroll
      for(int r=0;r<4;r++){
        float a = ((const float*)&a4[r])[kk];
        c[r][0] += a*bv.x; c[r][1] += a*bv.y; c[r][2] += a*bv.z; c[r][3] += a*bv.w;
      }
    }
  }
}

// C[4][4] += A * (dg*I - B)   (Newton-Schulz steps)
__device__ __forceinline__ void mm_tile_diag(float c[4][4], const float (*A)[PAD], const float (*B)[PAD], int i0, int j0, float dg){
  #pragma unroll 4
  for(int k=0;k<64;k+=4){
    float4 a4[4];
    #pragma unroll
    for(int r=0;r<4;r++) a4[r] = ld4(&A[i0+r][k]);
    #pragma unroll
    for(int kk=0;kk<4;kk++){
      float4 bv = ld4(&B[k+kk][j0]);
      float b0=-bv.x, b1=-bv.y, b2=-bv.z, b3=-bv.w;
      int dd = k+kk-j0;
      if(dd==0) b0+=dg; else if(dd==1) b1+=dg; else if(dd==2) b2+=dg; else if(dd==3) b3+=dg;
      #pragma unroll
      for(int r=0;r<4;r++){
        float a = ((const float*)&a4[r])[kk];
        c[r][0]+=a*b0; c[r][1]+=a*b1; c[r][2]+=a*b2; c[r][3]+=a*b3;
      }
    }
  }
}

// ---------------- 1. landmark pooling (reads Q,K once; writes scaled QL,KL) ----------------
__global__ __launch_bounds__(256) void pool_kernel(const float* __restrict__ Qg, const float* __restrict__ Kg, float* __restrict__ ws){
  int bx = blockIdx.x;              // 48 heads * 2 tensors * 16 landmark-groups = 1536
  int head = bx >> 5;
  int rest = bx & 31;
  int tensor = rest >> 4;           // 0:Q 1:K
  int l0 = (rest & 15) * 4;
  int t = threadIdx.x;
  int ll = t >> 6;                  // wave id -> local landmark
  int lane = t & 63;
  int d4 = (lane & 15) * 4;
  int rq = lane >> 4;               // row phase 0..3
  const float* src = tensor ? Kg : Qg;
  float* dst = ws + (tensor ? OFF_KL : OFF_QL);
  int l = l0 + ll;
  const float* base = src + ((size_t)head*SEQ + (size_t)l*SEG)*DIM + d4;
  float sx=0.f, sy=0.f, sz=0.f, sw=0.f;
  #pragma unroll 4
  for(int r=rq; r<SEG; r+=4){
    float4 v = ld4(base + (size_t)r*DIM);
    sx+=v.x; sy+=v.y; sz+=v.z; sw+=v.w;
  }
  sx += __shfl_xor(sx,16); sy += __shfl_xor(sy,16); sz += __shfl_xor(sz,16); sw += __shfl_xor(sw,16);
  sx += __shfl_xor(sx,32); sy += __shfl_xor(sy,32); sz += __shfl_xor(sz,32); sw += __shfl_xor(sw,32);
  if(rq==0){
    const float sc = INV_SCALE / 64.0f;
    float4 o; o.x=sx*sc; o.y=sy*sc; o.z=sz*sc; o.w=sw*sc;
    st4(dst + ((size_t)head*64 + l)*DIM + d4, o);
  }
}

// ---------------- 2. kernel_2 softmax + per-head L1 row/col max ----------------
__global__ __launch_bounds__(256) void k2_kernel(float* __restrict__ ws){
  __shared__ float sQ[64][65];
  __shared__ float sK[64][65];
  __shared__ float sE[64][65];
  __shared__ float red[128];
  int h = blockIdx.x, t = threadIdx.x;
  const float* QL = ws + OFF_QL + (size_t)h*4096;
  const float* KL = ws + OFF_KL + (size_t)h*4096;
  for(int i=t;i<4096;i+=256){ sQ[i>>6][i&63]=QL[i]; sK[i>>6][i&63]=KL[i]; }
  __syncthreads();
  int i = t>>2, q = t&3;
  float l[16];
  #pragma unroll
  for(int jj=0;jj<16;jj++){
    int j = q*16+jj;
    float s=0.f;
    for(int d=0;d<64;d++) s += sQ[i][d]*sK[j][d];
    l[jj]=s;
  }
  float mx = l[0];
  #pragma unroll
  for(int jj=1;jj<16;jj++) mx = fmaxf(mx,l[jj]);
  mx = fmaxf(mx, __shfl_xor(mx,1));
  mx = fmaxf(mx, __shfl_xor(mx,2));
  float sum=0.f;
  #pragma unroll
  for(int jj=0;jj<16;jj++){ l[jj]=__expf(l[jj]-mx); sum+=l[jj]; }
  sum += __shfl_xor(sum,1);
  sum += __shfl_xor(sum,2);
  float inv = 1.0f/sum;
  #pragma unroll
  for(int jj=0;jj<16;jj++) sE[i][q*16+jj] = l[jj]*inv;
  __syncthreads();
  float* K2 = ws + OFF_K2 + (size_t)h*4096;
  for(int idx=t; idx<4096; idx+=256) K2[idx] = sE[idx>>6][idx&63];
  if(t<64){
    float cs=0.f, rs=0.f;
    for(int r=0;r<64;r++){ cs += sE[r][t]; rs += sE[t][r]; }
    red[t]=cs; red[64+t]=rs;
  }
  __syncthreads();
  if(t==0){
    float cm=0.f, rm=0.f;
    for(int j=0;j<64;j++){ cm=fmaxf(cm,red[j]); rm=fmaxf(rm,red[64+j]); }
    ws[OFF_CMAX+h]=cm; ws[OFF_RMAX+h]=rm;
  }
}

// ---------------- 3. fused: Newton-Schulz (blocks 0..47, MFMA bf16x3 + fp32 last iter) ||
//                  kernel_3@V partials (blocks 48..431, MFMA bf16x3) ----------------
__global__ __launch_bounds__(256) void fused_kernel(const float* __restrict__ Kg, const float* __restrict__ Vg, float* __restrict__ ws){
  __shared__ __align__(16) unsigned char smem[74752];
  __shared__ float sscale;
  int bid = blockIdx.x, t = threadIdx.x;
  const int lane=t&63, w=t>>6, ln=lane&15, g=lane>>4;
  const int rr=t>>4, c4=(t&15)*4;
  if(bid < BH){
    // ---- Newton-Schulz pseudo-inverse of kernel_2, head=bid ----
    // Iterate kept as bf16 hi/lo in LDS in BOTH orientations:
    //   R = Vm rows, U = Vm^T rows. Km lives in per-wave A-fragment registers.
    // LDS slots (ushort offsets, each 4608 = 64*BSTR):
    //   U:[0,9216) R:[9216,18432) C(KV/G13):[18432,27648) G(G7/G15):[27648,36864)
    int h = bid;
    const float* K2 = ws + OFF_K2 + (size_t)h*4096;
    unsigned short* Uh=(unsigned short*)smem;
    unsigned short* Ul=Uh+4608;
    unsigned short* Rh=Uh+9216;
    unsigned short* Rl=Uh+13824;
    unsigned short* Ch=Uh+18432;
    unsigned short* Cl=Uh+23040;
    unsigned short* Gh=Uh+27648;
    unsigned short* Gl=Uh+32256;
    // Km A-frags from global K2 (row 16w+ln, k=32kh+8g+e), unscaled
    short8 kmh[2],kml[2];
    #pragma unroll
    for(int kh=0;kh<2;kh++){
      const float* p=K2+(16*w+ln)*64+32*kh+8*g;
      float4 x0=ld4(p), x1=ld4(p+4);
      uint2 h0,l0,h1,l1; split4(x0,h0,l0); split4(x1,h1,l1);
      kmh[kh]=mk8(h0,h1); kml[kh]=mk8(l0,l1);
    }
    // global scale = 1/(max col-L1 * max row-L1) over all heads — wave-parallel reduce
    if(t<64){
      float cm=(lane<BH)?ws[OFF_CMAX+lane]:0.f;
      float rm=(lane<BH)?ws[OFF_RMAX+lane]:0.f;
      #pragma unroll
      for(int s=32;s>=1;s>>=1){ cm=fmaxf(cm,__shfl_xor(cm,s)); rm=fmaxf(rm,__shfl_xor(rm,s)); }
      if(t==0) sscale=1.0f/(cm*rm);
    }
    __syncthreads();
    float scale=sscale;
    // stage U0 = scale*Km (rows) ; R0 = scale*Km^T (transpose scatter)
    #pragma unroll
    for(int gg=0;gg<4;gg++){
      int m=rr+16*gg;
      float4 v=ld4(K2+m*64+c4);
      v.x*=scale; v.y*=scale; v.z*=scale; v.w*=scale;
      uint2 hi,lo; split4(v,hi,lo);
      *reinterpret_cast<uint2*>(Uh+m*BSTR+c4)=hi;
      *reinterpret_cast<uint2*>(Ul+m*BSTR+c4)=lo;
      float fv[4]={v.x,v.y,v.z,v.w};
      #pragma unroll
      for(int e=0;e<4;e++){
        unsigned short hv=bfh_(fv[e]);
        Rh[(c4+e)*BSTR+m]=hv;
        Rl[(c4+e)*BSTR+m]=bfl_(fv[e],hv);
      }
    }
    __syncthreads();
    f32x4 dA[4];
    short8 ah[2],al[2];
    for(int it=0; it<5; it++){
      // ---- S1: KV = Km @ Vm  (B-frag rows from U = Vm^T) ----
      #pragma unroll
      for(int ni=0;ni<4;ni++){
        f32x4 d=(f32x4){0.f,0.f,0.f,0.f};
        #pragma unroll
        for(int kh=0;kh<2;kh++){
          int bb=(16*ni+ln)*BSTR+32*kh+8*g;
          short8 bh=*reinterpret_cast<const short8*>(Uh+bb);
          short8 bl=*reinterpret_cast<const short8*>(Ul+bb);
          d=MFMA16(kmh[kh],bh,d); d=MFMA16(kmh[kh],bl,d); d=MFMA16(kml[kh],bh,d);
        }
        dA[ni]=d;
      }
      // write KV row-major (C slot) and G7=(7I-KV)^T (G slot)
      #pragma unroll
      for(int ni=0;ni<4;ni++){
        int j=16*ni+ln;
        float4 tv; float* pv=(float*)&tv;
        #pragma unroll
        for(int r=0;r<4;r++){
          float v=dA[ni][r];
          int i=16*w+4*g+r;
          unsigned short hv=bfh_(v);
          Ch[i*BSTR+j]=hv; Cl[i*BSTR+j]=bfl_(v,hv);
          pv[r]=((i==j)?7.0f:0.0f)-v;
        }
        uint2 hi,lo; split4(tv,hi,lo);
        *reinterpret_cast<uint2*>(Gh+j*BSTR+16*w+4*g)=hi;
        *reinterpret_cast<uint2*>(Gl+j*BSTR+16*w+4*g)=lo;
      }
      __syncthreads();
      // ---- S2: B2 = KV @ (7I-KV) ; cache KV A-frags for S3 ----
      #pragma unroll
      for(int kh=0;kh<2;kh++){
        int ab=(16*w+ln)*BSTR+32*kh+8*g;
        ah[kh]=*reinterpret_cast<const short8*>(Ch+ab);
        al[kh]=*reinterpret_cast<const short8*>(Cl+ab);
      }
      #pragma unroll
      for(int ni=0;ni<4;ni++){
        f32x4 d=(f32x4){0.f,0.f,0.f,0.f};
        #pragma unroll
        for(int kh=0;kh<2;kh++){
          int bb=(16*ni+ln)*BSTR+32*kh+8*g;
          short8 bh=*reinterpret_cast<const short8*>(Gh+bb);
          short8 bl=*reinterpret_cast<const short8*>(Gl+bb);
          d=MFMA16(ah[kh],bh,d); d=MFMA16(ah[kh],bl,d); d=MFMA16(al[kh],bh,d);
        }
        dA[ni]=d;
      }
      __syncthreads();
      // write G15=(15I-B2)^T into G slot
      #pragma unroll
      for(int ni=0;ni<4;ni++){
        int j=16*ni+ln;
        float4 tv; float* pv=(float*)&tv;
        #pragma unroll
        for(int r=0;r<4;r++){ int i=16*w+4*g+r; pv[r]=((i==j)?15.0f:0.0f)-dA[ni][r]; }
        uint2 hi,lo; split4(tv,hi,lo);
        *reinterpret_cast<uint2*>(Gh+j*BSTR+16*w+4*g)=hi;
        *reinterpret_cast<uint2*>(Gl+j*BSTR+16*w+4*g)=lo;
      }
      __syncthreads();
      // ---- S3: B1' = KV @ (15I-B2)  (A cached) ----
      #pragma unroll
      for(int ni=0;ni<4;ni++){
        f32x4 d=(f32x4){0.f,0.f,0.f,0.f};
        #pragma unroll
        for(int kh=0;kh<2;kh++){
          int bb=(16*ni+ln)*BSTR+32*kh+8*g;
          short8 bh=*reinterpret_cast<const short8*>(Gh+bb);
          short8 bl=*reinterpret_cast<const short8*>(Gl+bb);
          d=MFMA16(ah[kh],bh,d); d=MFMA16(ah[kh],bl,d); d=MFMA16(al[kh],bh,d);
        }
        dA[ni]=d;
      }
      __syncthreads();
      // write G13=(13I-B1')^T into C slot (KV dead)
      #pragma unroll
      for(int ni=0;ni<4;ni++){
        int j=16*ni+ln;
        float4 tv; float* pv=(float*)&tv;
        #pragma unroll
        for(int r=0;r<4;r++){ int i=16*w+4*g+r; pv[r]=((i==j)?13.0f:0.0f)-dA[ni][r]; }
        uint2 hi,lo; split4(tv,hi,lo);
        *reinterpret_cast<uint2*>(Ch+j*BSTR+16*w+4*g)=hi;
        *reinterpret_cast<uint2*>(Cl+j*BSTR+16*w+4*g)=lo;
      }
      __syncthreads();
      // ---- S4: Vm' = 0.25 * Vm @ (13I-B1')  (A from R rows, B from C slot) ----
      #pragma unroll
      for(int kh=0;kh<2;kh++){
        int ab=(16*w+ln)*BSTR+32*kh+8*g;
        ah[kh]=*reinterpret_cast<const short8*>(Rh+ab);
        al[kh]=*reinterpret_cast<const short8*>(Rl+ab);
      }
      #pragma unroll
      for(int ni=0;ni<4;ni++){
        f32x4 d=(f32x4){0.f,0.f,0.f,0.f};
        #pragma unroll
        for(int kh=0;kh<2;kh++){
          int bb=(16*ni+ln)*BSTR+32*kh+8*g;
          short8 bh=*reinterpret_cast<const short8*>(Ch+bb);
          short8 bl=*reinterpret_cast<const short8*>(Cl+bb);
          d=MFMA16(ah[kh],bh,d); d=MFMA16(ah[kh],bl,d); d=MFMA16(al[kh],bh,d);
        }
        dA[ni]=d;
      }
      __syncthreads();
      // write R' row-major + U'=Vm'^T
      #pragma unroll
      for(int ni=0;ni<4;ni++){
        int j=16*ni+ln;
        float4 tv; float* pv=(float*)&tv;
        #pragma unroll
        for(int r=0;r<4;r++){
          float v=0.25f*dA[ni][r];
          int i=16*w+4*g+r;
          unsigned short hv=bfh_(v);
          Rh[i*BSTR+j]=hv; Rl[i*BSTR+j]=bfl_(v,hv);
          pv[r]=v;
        }
        uint2 hi,lo; split4(tv,hi,lo);
        *reinterpret_cast<uint2*>(Uh+j*BSTR+16*w+4*g)=hi;
        *reinterpret_cast<uint2*>(Ul+j*BSTR+16*w+4*g)=lo;
      }
      __syncthreads();
    }
    // ---- final (6th) iteration in fp32 for output precision ----
    float (*Vmf)[PAD]=(float(*)[PAD])(smem+36864);   // overlays C slot (dead)
    for(int i=t;i<4096;i+=256){
      int r_=i>>6, c_=i&63;
      float v=__uint_as_float(((unsigned)Rh[r_*BSTR+c_])<<16)
             +__uint_as_float(((unsigned)Rl[r_*BSTR+c_])<<16);
      Vmf[r_][c_]=v;
    }
    __syncthreads();
    float (*B1)[PAD]=(float(*)[PAD])(smem);          // overlays U slot (dead)
    float (*B2)[PAD]=(float(*)[PAD])(smem+17408);    // overlays R slot (dead after Vmf build)
    int i0=(t>>4)*4, j0=(t&15)*4;
    { // B1 = Km @ Vm   (A rows from global K2, L2-hot)
      float c[4][4]={};
      mm_tile_gA(c,K2,Vmf,i0,j0);
      #pragma unroll
      for(int r=0;r<4;r++){ float4 o; o.x=c[r][0];o.y=c[r][1];o.z=c[r][2];o.w=c[r][3]; st4(&B1[i0+r][j0],o); }
      __syncthreads();
    }
    { // B2 = KV @ (7I - KV)
      float c[4][4]={};
      mm_tile_diag(c,B1,B1,i0,j0,7.0f);
      #pragma unroll
      for(int r=0;r<4;r++){ float4 o; o.x=c[r][0];o.y=c[r][1];o.z=c[r][2];o.w=c[r][3]; st4(&B2[i0+r][j0],o); }
      __syncthreads();
    }
    { // B1 = KV @ (15I - B2)   (in-place)
      float c[4][4]={};
      mm_tile_diag(c,B1,B2,i0,j0,15.0f);
      __syncthreads();
      #pragma unroll
      for(int r=0;r<4;r++){ float4 o; o.x=c[r][0];o.y=c[r][1];o.z=c[r][2];o.w=c[r][3]; st4(&B1[i0+r][j0],o); }
      __syncthreads();
    }
    { // Vm = 0.25 * Vm @ (13I - B1)   (in-place)
      float c[4][4]={};
      mm_tile_diag(c,Vmf,B1,i0,j0,13.0f);
      __syncthreads();
      #pragma unroll
      for(int r=0;r<4;r++){ float4 o; o.x=0.25f*c[r][0];o.y=0.25f*c[r][1];o.z=0.25f*c[r][2];o.w=0.25f*c[r][3]; st4(&Vmf[i0+r][j0],o); }
      __syncthreads();
    }
    float* W = ws + OFF_W + (size_t)h*4096;
    for(int i=t;i<4096;i+=256) W[i] = Vmf[i>>6][i&63];
  } else {
    // ---- kernel_3 @ V partial via MFMA bf16x3: block = (head, 512-key chunk) ----
    int b = bid - BH;
    int h = b >> 3, ch = b & 7;
    unsigned short* QLh=(unsigned short*)smem;   // each array 64*BSTR ushorts = 9216 B
    unsigned short* QLl=QLh+4608;
    unsigned short* Kth=QLh+9216;
    unsigned short* Ktl=QLh+13824;
    unsigned short* VTh=QLh+18432;
    unsigned short* VTl=QLh+23040;
    unsigned short* PTh=QLh+27648;
    unsigned short* PTl=QLh+32256;
    float* sden=(float*)(smem+73728);            // [4][64]
    const float* QL = ws + OFF_QL + (size_t)h*4096;
    // stage QL (hi/lo bf16, m-major rows, k=d contiguous)
    #pragma unroll
    for(int gg=0;gg<4;gg++){
      int m=rr+16*gg;
      float4 v=ld4(QL+m*64+c4);
      uint2 hi,lo; split4(v,hi,lo);
      *reinterpret_cast<uint2*>(QLh+m*BSTR+c4)=hi;
      *reinterpret_cast<uint2*>(QLl+m*BSTR+c4)=lo;
    }
    const size_t kbase=((size_t)h*SEQ+(size_t)ch*CHUNK)*DIM;
    // prologue: prefetch tile 0 into registers
    float4 kr[4],vr[4];
    #pragma unroll
    for(int gg=0;gg<4;gg++){
      size_t off=kbase+(size_t)(rr+16*gg)*DIM+c4;
      kr[gg]=ld4(Kg+off); vr[gg]=ld4(Vg+off);
    }
    f32x4 acc[4];
    #pragma unroll
    for(int ni=0;ni<4;ni++) acc[ni]=(f32x4){0.f,0.f,0.f,0.f};
    float den_acc[4]={0.f,0.f,0.f,0.f};
    for(int tile=0;tile<8;tile++){
      __syncthreads();   // prev tile's LDS reads done (also covers QL staging on first pass)
      // stage K (scaled, s'-major) and V^T (d-major, s'-contiguous, XOR-swizzled scatter)
      #pragma unroll
      for(int gg=0;gg<4;gg++){
        int r=rr+16*gg;
        float4 kv=kr[gg];
        kv.x*=INV_SCALE; kv.y*=INV_SCALE; kv.z*=INV_SCALE; kv.w*=INV_SCALE;
        uint2 hi,lo; split4(kv,hi,lo);
        *reinterpret_cast<uint2*>(Kth+r*BSTR+c4)=hi;
        *reinterpret_cast<uint2*>(Ktl+r*BSTR+c4)=lo;
        float fv[4]={vr[gg].x,vr[gg].y,vr[gg].z,vr[gg].w};
        #pragma unroll
        for(int e=0;e<4;e++){
          int d=c4+e;
          unsigned short hv=bfh_(fv[e]);
          unsigned short lv=bfl_(fv[e],hv);
          int sp = r ^ (((d>>2)&7)<<3);   // swizzle s' bits 3..5 by d bits 2..4 (store-side)
          VTh[d*BSTR+sp]=hv; VTl[d*BSTR+sp]=lv;
        }
      }
      // issue next tile's global loads (latency hidden under the MFMA phases)
      if(tile<7){
        #pragma unroll
        for(int gg=0;gg<4;gg++){
          size_t off=kbase+(size_t)((tile+1)*64+rr+16*gg)*DIM+c4;
          kr[gg]=ld4(Kg+off); vr[gg]=ld4(Vg+off);
        }
      }
      __syncthreads();
      // ---- logits: D[s'][m] = K_scaled . QL ; wave w owns s' rows 16w..16w+15 ----
      short8 kah[2],kal[2];
      #pragma unroll
      for(int kh=0;kh<2;kh++){
        int ab=(16*w+ln)*BSTR+32*kh+8*g;
        kah[kh]=*reinterpret_cast<const short8*>(Kth+ab);
        kal[kh]=*reinterpret_cast<const short8*>(Ktl+ab);
      }
      #pragma unroll
      for(int ni=0;ni<4;ni++){
        f32x4 dl=(f32x4){0.f,0.f,0.f,0.f};
        #pragma unroll
        for(int kh=0;kh<2;kh++){
          int bb=(16*ni+ln)*BSTR+32*kh+8*g;
          short8 bh=*reinterpret_cast<const short8*>(QLh+bb);
          short8 bl=*reinterpret_cast<const short8*>(QLl+bb);
          dl=MFMA16(kah[kh],bh,dl);
          dl=MFMA16(kah[kh],bl,dl);
          dl=MFMA16(kal[kh],bh,dl);
        }
        // P = exp(logits); D layout: row s' = 16w + 4g + reg, col m = 16ni + ln
        float p0=__expf(dl[0]), p1=__expf(dl[1]), p2=__expf(dl[2]), p3=__expf(dl[3]);
        den_acc[ni]+=p0+p1+p2+p3;
        unsigned short h0=bfh_(p0),h1=bfh_(p1),h2=bfh_(p2),h3=bfh_(p3);
        unsigned short l0=bfl_(p0,h0),l1=bfl_(p1,h1),l2=bfl_(p2,h2),l3=bfl_(p3,h3);
        int pb=(16*ni+ln)*BSTR+16*w+4*g;   // PT[m][s'] s'-contiguous
        *reinterpret_cast<uint2*>(PTh+pb)=make_uint2((unsigned)h0|((unsigned)h1<<16),(unsigned)h2|((unsigned)h3<<16));
        *reinterpret_cast<uint2*>(PTl+pb)=make_uint2((unsigned)l0|((unsigned)l1<<16),(unsigned)l2|((unsigned)l3<<16));
      }
      __syncthreads();
      // ---- PV: acc[m][d] += P^T . V ; wave w owns m rows 16w..16w+15 ----
      short8 pah[2],pal[2];
      #pragma unroll
      for(int kh=0;kh<2;kh++){
        int pb=(16*w+ln)*BSTR+32*kh+8*g;
        pah[kh]=*reinterpret_cast<const short8*>(PTh+pb);
        pal[kh]=*reinterpret_cast<const short8*>(PTl+pb);
      }
      #pragma unroll
      for(int ni=0;ni<4;ni++){
        int row=16*ni+ln;                 // row = d
        int swz=((row>>2)&7)<<3;
        #pragma unroll
        for(int kh=0;kh<2;kh++){
          int vb=row*BSTR+((32*kh+8*g)^swz);   // compensate store-side swizzle
          short8 vh=*reinterpret_cast<const short8*>(VTh+vb);
          short8 vl=*reinterpret_cast<const short8*>(VTl+vb);
          acc[ni]=MFMA16(pah[kh],vh,acc[ni]);
          acc[ni]=MFMA16(pah[kh],vl,acc[ni]);
          acc[ni]=MFMA16(pal[kh],vh,acc[ni]);
        }
      }
    }
    // epilogue: MNUM partials (D layout: row m = 16w+4g+r, col d = 16ni+ln)
    float* num = ws + OFF_MNUM + (size_t)b*4096;
    #pragma unroll
    for(int ni=0;ni<4;ni++){
      #pragma unroll
      for(int r=0;r<4;r++) num[(16*w+4*g+r)*64+16*ni+ln]=acc[ni][r];
      den_acc[ni]+=__shfl_xor(den_acc[ni],16);
      den_acc[ni]+=__shfl_xor(den_acc[ni],32);
    }
    if(lane<16){
      #pragma unroll
      for(int ni=0;ni<4;ni++) sden[w*64+16*ni+lane]=den_acc[ni];
    }
    __syncthreads();
    if(t<64) ws[OFF_MDEN+(size_t)b*64+t]=sden[t]+sden[64+t]+sden[128+t]+sden[192+t];
  }
}

// ---------------- 4. combine partials -> M, then P = W @ M ----------------
__global__ __launch_bounds__(256) void combine_kernel(float* __restrict__ ws){
  __shared__ float sW[64][PAD];
  __shared__ float sM[64][PAD];
  __shared__ float sden[64];
  int h=blockIdx.x, t=threadIdx.x;
  if(t<64){
    float s=0.f;
    for(int c=0;c<NCHUNK;c++) s += ws[OFF_MDEN + ((size_t)h*NCHUNK+c)*64 + t];
    sden[t]=1.0f/s;
  }
  for(int i=t;i<4096;i+=256) sW[i>>6][i&63] = ws[OFF_W + (size_t)h*4096 + i];
  __syncthreads();
  for(int i=t;i<1024;i+=256){
    int m=i>>4, d4=(i&15)*4;
    float sx=0.f,sy=0.f,sz=0.f,sw2=0.f;
    for(int c=0;c<NCHUNK;c++){
      float4 v = ld4(ws + OFF_MNUM + ((size_t)h*NCHUNK+c)*4096 + m*64 + d4);
      sx+=v.x; sy+=v.y; sz+=v.z; sw2+=v.w;
    }
    float iv = sden[m];
    float4 o; o.x=sx*iv; o.y=sy*iv; o.z=sz*iv; o.w=sw2*iv;
    st4(&sM[m][d4], o);
  }
  __syncthreads();
  int i0=(t>>4)*4, j0=(t&15)*4;
  float c[4][4]={};
  mm_tile(c, sW, sM, i0, j0);
  float* P = ws + OFF_P + (size_t)h*4096;
  #pragma unroll
  for(int r=0;r<4;r++){
    float4 o; o.x=c[r][0]; o.y=c[r][1]; o.z=c[r][2]; o.w=c[r][3];
    st4(P + (i0+r)*64 + j0, o);
  }
}

// ---------------- 5. X = rowsoftmax(Q . KL^T) @ P ----------------
__global__ __launch_bounds__(256) void final_kernel(const float* __restrict__ Qg, float* __restrict__ out, const float* __restrict__ ws){
  __shared__ float sKLT[64][PAD];
  __shared__ float sP[64][PAD];
  __shared__ float sQE[64][PAD];
  int bid=blockIdx.x, t=threadIdx.x;
  int h=bid>>6, s0=(bid&63)*64;
  const float* KL = ws + OFF_KL + (size_t)h*4096;
  const float* P  = ws + OFF_P  + (size_t)h*4096;
  const float* Qb = Qg + ((size_t)h*SEQ + (size_t)s0)*DIM;
  for(int i=t;i<1024;i+=256){
    int m=i>>4, d4=(i&15)*4;
    float4 v = ld4(KL + m*64 + d4);
    sKLT[d4+0][m]=v.x; sKLT[d4+1][m]=v.y; sKLT[d4+2][m]=v.z; sKLT[d4+3][m]=v.w;
    st4(&sP[m][d4], ld4(P + m*64 + d4));
    float4 q = ld4(Qb + (size_t)m*DIM + d4);
    q.x*=INV_SCALE; q.y*=INV_SCALE; q.z*=INV_SCALE; q.w*=INV_SCALE;
    st4(&sQE[m][d4], q);
  }
  __syncthreads();
  int i0=(t>>4)*4, j0=(t&15)*4;
  float l[4][4]={};
  mm_tile(l, sQE, sKLT, i0, j0);
  float e[4][4]; float rs[4];
  #pragma unroll
  for(int r=0;r<4;r++){
    float s=0.f;
    #pragma unroll
    for(int cc=0;cc<4;cc++){ e[r][cc]=__expf(l[r][cc]); s+=e[r][cc]; }
    rs[r]=s;
  }
  #pragma unroll
  for(int r=0;r<4;r++){
    rs[r]+=__shfl_xor(rs[r],1);
    rs[r]+=__shfl_xor(rs[r],2);
    rs[r]+=__shfl_xor(rs[r],4);
    rs[r]+=__shfl_xor(rs[r],8);
  }
  __syncthreads();    // all reads of sQE (as Q) done -> overwrite with E
  #pragma unroll
  for(int r=0;r<4;r++){ float4 o; o.x=e[r][0]; o.y=e[r][1]; o.z=e[r][2]; o.w=e[r][3]; st4(&sQE[i0+r][j0], o); }
  __syncthreads();
  float c[4][4]={};
  mm_tile(c, sQE, sP, i0, j0);
  #pragma unroll
  for(int r=0;r<4;r++){
    float iv = 1.0f/rs[r];
    float4 o; o.x=c[r][0]*iv; o.y=c[r][1]*iv; o.z=c[r][2]*iv; o.w=c[r][3]*iv;
    st4(out + ((size_t)h*SEQ + (size_t)(s0+i0+r))*DIM + j0, o);
  }
}

extern "C" void kernel_launch(void* const* d_in, const int* in_sizes, int n_in,
                              void* d_out, int out_size, void* d_ws, size_t ws_size,
                              hipStream_t stream) {
  const float* Q = (const float*)d_in[0];
  const float* K = (const float*)d_in[1];
  const float* V = (const float*)d_in[2];
  float* out = (float*)d_out;
  float* ws  = (float*)d_ws;

  pool_kernel   <<<BH*32, 256, 0, stream>>>(Q, K, ws);
  k2_kernel     <<<BH,    256, 0, stream>>>(ws);
  fused_kernel  <<<BH + BH*NCHUNK, 256, 0, stream>>>(K, V, ws);
  combine_kernel<<<BH,    256, 0, stream>>>(ws);
  final_kernel  <<<BH*64, 256, 0, stream>>>(Q, out, ws);
}

// Round 6
// 244.119 us; speedup vs baseline: 1.2864x; 1.1047x over previous
//
#include <hip/hip_runtime.h>
#include <cstdint>

#define BH 48
#define SEQ 4096
#define DIM 64
#define SEG 64
#define NCHUNK 8
#define CHUNK 512
#define PAD 68
#define BSTR 72   // bf16 row stride in ushorts (144 B = 16B-aligned)

static constexpr float INV_SCALE = 0.35355339059327379f; // 1/sqrt(sqrt(64))

// workspace float offsets
#define OFF_QL   0u        // 48*4096
#define OFF_KL   196608u   // 48*4096
#define OFF_K2   393216u   // 48*4096
#define OFF_W    589824u   // 48*4096
#define OFF_P    786432u   // 48*4096
#define OFF_MNUM 983040u   // 48*8*4096
#define OFF_MDEN 2555904u  // 48*8*64
#define OFF_CMAX 2580480u  // 48
#define OFF_RMAX 2580528u  // 48  (total 2580576 floats ~ 10.3 MB)

typedef __attribute__((ext_vector_type(8))) short short8;
typedef __attribute__((ext_vector_type(4))) float f32x4;
#define MFMA16(a,b,c) __builtin_amdgcn_mfma_f32_16x16x32_bf16(a,b,c,0,0,0)

__device__ __forceinline__ float4 ld4(const float* p){ return *reinterpret_cast<const float4*>(p); }
__device__ __forceinline__ void st4(float* p, float4 v){ *reinterpret_cast<float4*>(p) = v; }

// bf16 high part (round-to-nearest-even) and low residual part
__device__ __forceinline__ unsigned short bfh_(float x){
  unsigned u = __float_as_uint(x);
  return (unsigned short)((u + 0x7fffu + ((u>>16)&1u)) >> 16);
}
__device__ __forceinline__ unsigned short bfl_(float x, unsigned short h){
  float r = x - __uint_as_float(((unsigned)h)<<16);
  return (unsigned short)(__float_as_uint(r) >> 16);   // truncate; residual-of-residual ~2^-17
}
__device__ __forceinline__ void split4(float4 v, uint2& hi, uint2& lo){
  unsigned short h0=bfh_(v.x), h1=bfh_(v.y), h2=bfh_(v.z), h3=bfh_(v.w);
  unsigned short l0=bfl_(v.x,h0), l1=bfl_(v.y,h1), l2=bfl_(v.z,h2), l3=bfl_(v.w,h3);
  hi = make_uint2((unsigned)h0 | ((unsigned)h1<<16), (unsigned)h2 | ((unsigned)h3<<16));
  lo = make_uint2((unsigned)l0 | ((unsigned)l1<<16), (unsigned)l2 | ((unsigned)l3<<16));
}
__device__ __forceinline__ short8 mk8(uint2 a, uint2 b){
  union { short8 s; uint4 u; } x; x.u = make_uint4(a.x,a.y,b.x,b.y); return x.s;
}

// C[4][4] += A[i0..i0+3][:] * B[:][j0..j0+3], 64-deep, LDS operands (pad=68 keeps 16B align)
__device__ __forceinline__ void mm_tile(float c[4][4], const float (*A)[PAD], const float (*B)[PAD], int i0, int j0){
  #pragma unroll 4
  for(int k=0;k<64;k+=4){
    float4 a4[4];
    #pragma unroll
    for(int r=0;r<4;r++) a4[r] = ld4(&A[i0+r][k]);
    #pragma unroll
    for(int kk=0;kk<4;kk++){
      float4 bv = ld4(&B[k+kk][j0]);
      #pragma unroll
      for(int r=0;r<4;r++){
        float a = ((const float*)&a4[r])[kk];
        c[r][0] += a*bv.x; c[r][1] += a*bv.y; c[r][2] += a*bv.z; c[r][3] += a*bv.w;
      }
    }
  }
}

// same, but A rows come straight from global (row-major, stride 64) — L2-resident broadcast reads
__device__ __forceinline__ void mm_tile_gA(float c[4][4], const float* __restrict__ gA, const float (*B)[PAD], int i0, int j0){
  #pragma unroll 4
  for(int k=0;k<64;k+=4){
    float4 a4[4];
    #pragma unroll
    for(int r=0;r<4;r++) a4[r] = ld4(gA + (i0+r)*64 + k);
    #pragma unroll
    for(int kk=0;kk<4;kk++){
      float4 bv = ld4(&B[k+kk][j0]);
      #pragma unroll
      for(int r=0;r<4;r++){
        float a = ((const float*)&a4[r])[kk];
        c[r][0] += a*bv.x; c[r][1] += a*bv.y; c[r][2] += a*bv.z; c[r][3] += a*bv.w;
      }
    }
  }
}

// C[4][4] += A * (dg*I - B)   (Newton-Schulz steps)
__device__ __forceinline__ void mm_tile_diag(float c[4][4], const float (*A)[PAD], const float (*B)[PAD], int i0, int j0, float dg){
  #pragma unroll 4
  for(int k=0;k<64;k+=4){
    float4 a4[4];
    #pragma unroll
    for(int r=0;r<4;r++) a4[r] = ld4(&A[i0+r][k]);
    #pragma unroll
    for(int kk=0;kk<4;kk++){
      float4 bv = ld4(&B[k+kk][j0]);
      float b0=-bv.x, b1=-bv.y, b2=-bv.z, b3=-bv.w;
      int dd = k+kk-j0;
      if(dd==0) b0+=dg; else if(dd==1) b1+=dg; else if(dd==2) b2+=dg; else if(dd==3) b3+=dg;
      #pragma unroll
      for(int r=0;r<4;r++){
        float a = ((const float*)&a4[r])[kk];
        c[r][0]+=a*b0; c[r][1]+=a*b1; c[r][2]+=a*b2; c[r][3]+=a*b3;
      }
    }
  }
}

// ---------------- 1. landmark pooling (reads Q,K once; writes scaled QL,KL) ----------------
__global__ __launch_bounds__(256) void pool_kernel(const float* __restrict__ Qg, const float* __restrict__ Kg, float* __restrict__ ws){
  int bx = blockIdx.x;              // 48 heads * 2 tensors * 16 landmark-groups = 1536
  int head = bx >> 5;
  int rest = bx & 31;
  int tensor = rest >> 4;           // 0:Q 1:K
  int l0 = (rest & 15) * 4;
  int t = threadIdx.x;
  int ll = t >> 6;                  // wave id -> local landmark
  int lane = t & 63;
  int d4 = (lane & 15) * 4;
  int rq = lane >> 4;               // row phase 0..3
  const float* src = tensor ? Kg : Qg;
  float* dst = ws + (tensor ? OFF_KL : OFF_QL);
  int l = l0 + ll;
  const float* base = src + ((size_t)head*SEQ + (size_t)l*SEG)*DIM + d4;
  float sx=0.f, sy=0.f, sz=0.f, sw=0.f;
  #pragma unroll 4
  for(int r=rq; r<SEG; r+=4){
    float4 v = ld4(base + (size_t)r*DIM);
    sx+=v.x; sy+=v.y; sz+=v.z; sw+=v.w;
  }
  sx += __shfl_xor(sx,16); sy += __shfl_xor(sy,16); sz += __shfl_xor(sz,16); sw += __shfl_xor(sw,16);
  sx += __shfl_xor(sx,32); sy += __shfl_xor(sy,32); sz += __shfl_xor(sz,32); sw += __shfl_xor(sw,32);
  if(rq==0){
    const float sc = INV_SCALE / 64.0f;
    float4 o; o.x=sx*sc; o.y=sy*sc; o.z=sz*sc; o.w=sw*sc;
    st4(dst + ((size_t)head*64 + l)*DIM + d4, o);
  }
}

// ---------------- 2. kernel_2 softmax + per-head L1 row/col max ----------------
__global__ __launch_bounds__(256) void k2_kernel(float* __restrict__ ws){
  __shared__ float sQ[64][65];
  __shared__ float sK[64][65];
  __shared__ float sE[64][65];
  __shared__ float red[128];
  int h = blockIdx.x, t = threadIdx.x;
  const float* QL = ws + OFF_QL + (size_t)h*4096;
  const float* KL = ws + OFF_KL + (size_t)h*4096;
  for(int i=t;i<4096;i+=256){ sQ[i>>6][i&63]=QL[i]; sK[i>>6][i&63]=KL[i]; }
  __syncthreads();
  int i = t>>2, q = t&3;
  float l[16];
  #pragma unroll
  for(int jj=0;jj<16;jj++){
    int j = q*16+jj;
    float s=0.f;
    for(int d=0;d<64;d++) s += sQ[i][d]*sK[j][d];
    l[jj]=s;
  }
  float mx = l[0];
  #pragma unroll
  for(int jj=1;jj<16;jj++) mx = fmaxf(mx,l[jj]);
  mx = fmaxf(mx, __shfl_xor(mx,1));
  mx = fmaxf(mx, __shfl_xor(mx,2));
  float sum=0.f;
  #pragma unroll
  for(int jj=0;jj<16;jj++){ l[jj]=__expf(l[jj]-mx); sum+=l[jj]; }
  sum += __shfl_xor(sum,1);
  sum += __shfl_xor(sum,2);
  float inv = 1.0f/sum;
  #pragma unroll
  for(int jj=0;jj<16;jj++) sE[i][q*16+jj] = l[jj]*inv;
  __syncthreads();
  float* K2 = ws + OFF_K2 + (size_t)h*4096;
  for(int idx=t; idx<4096; idx+=256) K2[idx] = sE[idx>>6][idx&63];
  if(t<64){
    float cs=0.f, rs=0.f;
    for(int r=0;r<64;r++){ cs += sE[r][t]; rs += sE[t][r]; }
    red[t]=cs; red[64+t]=rs;
  }
  __syncthreads();
  if(t==0){
    float cm=0.f, rm=0.f;
    for(int j=0;j<64;j++){ cm=fmaxf(cm,red[j]); rm=fmaxf(rm,red[64+j]); }
    ws[OFF_CMAX+h]=cm; ws[OFF_RMAX+h]=rm;
  }
}

// ---------------- 3. fused: Newton-Schulz (blocks 0..47, MFMA bf16x3 + fp32 last iter) ||
//                  kernel_3@V partials (blocks 48..431, MFMA bf16x3) ----------------
__global__ __launch_bounds__(256) void fused_kernel(const float* __restrict__ Kg, const float* __restrict__ Vg, float* __restrict__ ws){
  __shared__ __align__(16) unsigned char smem[74752];
  __shared__ float sscale;
  int bid = blockIdx.x, t = threadIdx.x;
  const int lane=t&63, w=t>>6, ln=lane&15, g=lane>>4;
  const int rr=t>>4, c4=(t&15)*4;
  if(bid < BH){
    // ---- Newton-Schulz pseudo-inverse of kernel_2, head=bid ----
    int h = bid;
    const float* K2 = ws + OFF_K2 + (size_t)h*4096;
    unsigned short* Uh=(unsigned short*)smem;
    unsigned short* Ul=Uh+4608;
    unsigned short* Rh=Uh+9216;
    unsigned short* Rl=Uh+13824;
    unsigned short* Ch=Uh+18432;
    unsigned short* Cl=Uh+23040;
    unsigned short* Gh=Uh+27648;
    unsigned short* Gl=Uh+32256;
    // Km A-frags from global K2 (row 16w+ln, k=32kh+8g+e), unscaled
    short8 kmh[2],kml[2];
    #pragma unroll
    for(int kh=0;kh<2;kh++){
      const float* p=K2+(16*w+ln)*64+32*kh+8*g;
      float4 x0=ld4(p), x1=ld4(p+4);
      uint2 h0,l0,h1,l1; split4(x0,h0,l0); split4(x1,h1,l1);
      kmh[kh]=mk8(h0,h1); kml[kh]=mk8(l0,l1);
    }
    // global scale = 1/(max col-L1 * max row-L1) over all heads — wave-parallel reduce
    if(t<64){
      float cm=(lane<BH)?ws[OFF_CMAX+lane]:0.f;
      float rm=(lane<BH)?ws[OFF_RMAX+lane]:0.f;
      #pragma unroll
      for(int s=32;s>=1;s>>=1){ cm=fmaxf(cm,__shfl_xor(cm,s)); rm=fmaxf(rm,__shfl_xor(rm,s)); }
      if(t==0) sscale=1.0f/(cm*rm);
    }
    __syncthreads();
    float scale=sscale;
    // stage U0 = scale*Km (rows) ; R0 = scale*Km^T (transpose scatter)
    #pragma unroll
    for(int gg=0;gg<4;gg++){
      int m=rr+16*gg;
      float4 v=ld4(K2+m*64+c4);
      v.x*=scale; v.y*=scale; v.z*=scale; v.w*=scale;
      uint2 hi,lo; split4(v,hi,lo);
      *reinterpret_cast<uint2*>(Uh+m*BSTR+c4)=hi;
      *reinterpret_cast<uint2*>(Ul+m*BSTR+c4)=lo;
      float fv[4]={v.x,v.y,v.z,v.w};
      #pragma unroll
      for(int e=0;e<4;e++){
        unsigned short hv=bfh_(fv[e]);
        Rh[(c4+e)*BSTR+m]=hv;
        Rl[(c4+e)*BSTR+m]=bfl_(fv[e],hv);
      }
    }
    __syncthreads();
    f32x4 dA[4];
    short8 ah[2],al[2];
    for(int it=0; it<5; it++){
      // ---- S1: KV = Km @ Vm  (B-frag rows from U = Vm^T) ----
      #pragma unroll
      for(int ni=0;ni<4;ni++){
        f32x4 d=(f32x4){0.f,0.f,0.f,0.f};
        #pragma unroll
        for(int kh=0;kh<2;kh++){
          int bb=(16*ni+ln)*BSTR+32*kh+8*g;
          short8 bh=*reinterpret_cast<const short8*>(Uh+bb);
          short8 bl=*reinterpret_cast<const short8*>(Ul+bb);
          d=MFMA16(kmh[kh],bh,d); d=MFMA16(kmh[kh],bl,d); d=MFMA16(kml[kh],bh,d);
        }
        dA[ni]=d;
      }
      // write KV row-major (C slot) and G7=(7I-KV)^T (G slot)
      #pragma unroll
      for(int ni=0;ni<4;ni++){
        int j=16*ni+ln;
        float4 tv; float* pv=(float*)&tv;
        #pragma unroll
        for(int r=0;r<4;r++){
          float v=dA[ni][r];
          int i=16*w+4*g+r;
          unsigned short hv=bfh_(v);
          Ch[i*BSTR+j]=hv; Cl[i*BSTR+j]=bfl_(v,hv);
          pv[r]=((i==j)?7.0f:0.0f)-v;
        }
        uint2 hi,lo; split4(tv,hi,lo);
        *reinterpret_cast<uint2*>(Gh+j*BSTR+16*w+4*g)=hi;
        *reinterpret_cast<uint2*>(Gl+j*BSTR+16*w+4*g)=lo;
      }
      __syncthreads();
      // ---- S2: B2 = KV @ (7I-KV) ; cache KV A-frags for S3 ----
      #pragma unroll
      for(int kh=0;kh<2;kh++){
        int ab=(16*w+ln)*BSTR+32*kh+8*g;
        ah[kh]=*reinterpret_cast<const short8*>(Ch+ab);
        al[kh]=*reinterpret_cast<const short8*>(Cl+ab);
      }
      #pragma unroll
      for(int ni=0;ni<4;ni++){
        f32x4 d=(f32x4){0.f,0.f,0.f,0.f};
        #pragma unroll
        for(int kh=0;kh<2;kh++){
          int bb=(16*ni+ln)*BSTR+32*kh+8*g;
          short8 bh=*reinterpret_cast<const short8*>(Gh+bb);
          short8 bl=*reinterpret_cast<const short8*>(Gl+bb);
          d=MFMA16(ah[kh],bh,d); d=MFMA16(ah[kh],bl,d); d=MFMA16(al[kh],bh,d);
        }
        dA[ni]=d;
      }
      __syncthreads();
      // write G15=(15I-B2)^T into G slot
      #pragma unroll
      for(int ni=0;ni<4;ni++){
        int j=16*ni+ln;
        float4 tv; float* pv=(float*)&tv;
        #pragma unroll
        for(int r=0;r<4;r++){ int i=16*w+4*g+r; pv[r]=((i==j)?15.0f:0.0f)-dA[ni][r]; }
        uint2 hi,lo; split4(tv,hi,lo);
        *reinterpret_cast<uint2*>(Gh+j*BSTR+16*w+4*g)=hi;
        *reinterpret_cast<uint2*>(Gl+j*BSTR+16*w+4*g)=lo;
      }
      __syncthreads();
      // ---- S3: B1' = KV @ (15I-B2)  (A cached) ----
      #pragma unroll
      for(int ni=0;ni<4;ni++){
        f32x4 d=(f32x4){0.f,0.f,0.f,0.f};
        #pragma unroll
        for(int kh=0;kh<2;kh++){
          int bb=(16*ni+ln)*BSTR+32*kh+8*g;
          short8 bh=*reinterpret_cast<const short8*>(Gh+bb);
          short8 bl=*reinterpret_cast<const short8*>(Gl+bb);
          d=MFMA16(ah[kh],bh,d); d=MFMA16(ah[kh],bl,d); d=MFMA16(al[kh],bh,d);
        }
        dA[ni]=d;
      }
      __syncthreads();
      // write G13=(13I-B1')^T into C slot (KV dead)
      #pragma unroll
      for(int ni=0;ni<4;ni++){
        int j=16*ni+ln;
        float4 tv; float* pv=(float*)&tv;
        #pragma unroll
        for(int r=0;r<4;r++){ int i=16*w+4*g+r; pv[r]=((i==j)?13.0f:0.0f)-dA[ni][r]; }
        uint2 hi,lo; split4(tv,hi,lo);
        *reinterpret_cast<uint2*>(Ch+j*BSTR+16*w+4*g)=hi;
        *reinterpret_cast<uint2*>(Cl+j*BSTR+16*w+4*g)=lo;
      }
      __syncthreads();
      // ---- S4: Vm' = 0.25 * Vm @ (13I-B1')  (A from R rows, B from C slot) ----
      #pragma unroll
      for(int kh=0;kh<2;kh++){
        int ab=(16*w+ln)*BSTR+32*kh+8*g;
        ah[kh]=*reinterpret_cast<const short8*>(Rh+ab);
        al[kh]=*reinterpret_cast<const short8*>(Rl+ab);
      }
      #pragma unroll
      for(int ni=0;ni<4;ni++){
        f32x4 d=(f32x4){0.f,0.f,0.f,0.f};
        #pragma unroll
        for(int kh=0;kh<2;kh++){
          int bb=(16*ni+ln)*BSTR+32*kh+8*g;
          short8 bh=*reinterpret_cast<const short8*>(Ch+bb);
          short8 bl=*reinterpret_cast<const short8*>(Cl+bb);
          d=MFMA16(ah[kh],bh,d); d=MFMA16(ah[kh],bl,d); d=MFMA16(al[kh],bh,d);
        }
        dA[ni]=d;
      }
      __syncthreads();
      // write R' row-major + U'=Vm'^T
      #pragma unroll
      for(int ni=0;ni<4;ni++){
        int j=16*ni+ln;
        float4 tv; float* pv=(float*)&tv;
        #pragma unroll
        for(int r=0;r<4;r++){
          float v=0.25f*dA[ni][r];
          int i=16*w+4*g+r;
          unsigned short hv=bfh_(v);
          Rh[i*BSTR+j]=hv; Rl[i*BSTR+j]=bfl_(v,hv);
          pv[r]=v;
        }
        uint2 hi,lo; split4(tv,hi,lo);
        *reinterpret_cast<uint2*>(Uh+j*BSTR+16*w+4*g)=hi;
        *reinterpret_cast<uint2*>(Ul+j*BSTR+16*w+4*g)=lo;
      }
      __syncthreads();
    }
    // ---- final (6th) iteration in fp32 for output precision ----
    float (*Vmf)[PAD]=(float(*)[PAD])(smem+36864);   // overlays C slot (dead)
    for(int i=t;i<4096;i+=256){
      int r_=i>>6, c_=i&63;
      float v=__uint_as_float(((unsigned)Rh[r_*BSTR+c_])<<16)
             +__uint_as_float(((unsigned)Rl[r_*BSTR+c_])<<16);
      Vmf[r_][c_]=v;
    }
    __syncthreads();
    float (*B1)[PAD]=(float(*)[PAD])(smem);          // overlays U slot (dead)
    float (*B2)[PAD]=(float(*)[PAD])(smem+17408);    // overlays R slot (dead after Vmf build)
    int i0=(t>>4)*4, j0=(t&15)*4;
    { // B1 = Km @ Vm   (A rows from global K2, L2-hot)
      float c[4][4]={};
      mm_tile_gA(c,K2,Vmf,i0,j0);
      #pragma unroll
      for(int r=0;r<4;r++){ float4 o; o.x=c[r][0];o.y=c[r][1];o.z=c[r][2];o.w=c[r][3]; st4(&B1[i0+r][j0],o); }
      __syncthreads();
    }
    { // B2 = KV @ (7I - KV)
      float c[4][4]={};
      mm_tile_diag(c,B1,B1,i0,j0,7.0f);
      #pragma unroll
      for(int r=0;r<4;r++){ float4 o; o.x=c[r][0];o.y=c[r][1];o.z=c[r][2];o.w=c[r][3]; st4(&B2[i0+r][j0],o); }
      __syncthreads();
    }
    { // B1 = KV @ (15I - B2)   (in-place)
      float c[4][4]={};
      mm_tile_diag(c,B1,B2,i0,j0,15.0f);
      __syncthreads();
      #pragma unroll
      for(int r=0;r<4;r++){ float4 o; o.x=c[r][0];o.y=c[r][1];o.z=c[r][2];o.w=c[r][3]; st4(&B1[i0+r][j0],o); }
      __syncthreads();
    }
    { // Vm = 0.25 * Vm @ (13I - B1)   (in-place)
      float c[4][4]={};
      mm_tile_diag(c,Vmf,B1,i0,j0,13.0f);
      __syncthreads();
      #pragma unroll
      for(int r=0;r<4;r++){ float4 o; o.x=0.25f*c[r][0];o.y=0.25f*c[r][1];o.z=0.25f*c[r][2];o.w=0.25f*c[r][3]; st4(&Vmf[i0+r][j0],o); }
      __syncthreads();
    }
    float* W = ws + OFF_W + (size_t)h*4096;
    for(int i=t;i<4096;i+=256) W[i] = Vmf[i>>6][i&63];
  } else {
    // ---- kernel_3 @ V partial via MFMA bf16x3: block = (head, 512-key chunk) ----
    int b = bid - BH;
    int h = b >> 3, ch = b & 7;
    unsigned short* QLh=(unsigned short*)smem;   // each array 64*BSTR ushorts = 9216 B
    unsigned short* QLl=QLh+4608;
    unsigned short* Kth=QLh+9216;
    unsigned short* Ktl=QLh+13824;
    unsigned short* VTh=QLh+18432;
    unsigned short* VTl=QLh+23040;
    unsigned short* PTh=QLh+27648;
    unsigned short* PTl=QLh+32256;
    float* sden=(float*)(smem+73728);            // [4][64]
    const float* QL = ws + OFF_QL + (size_t)h*4096;
    // stage QL (hi/lo bf16, m-major rows, k=d contiguous)
    #pragma unroll
    for(int gg=0;gg<4;gg++){
      int m=rr+16*gg;
      float4 v=ld4(QL+m*64+c4);
      uint2 hi,lo; split4(v,hi,lo);
      *reinterpret_cast<uint2*>(QLh+m*BSTR+c4)=hi;
      *reinterpret_cast<uint2*>(QLl+m*BSTR+c4)=lo;
    }
    const size_t kbase=((size_t)h*SEQ+(size_t)ch*CHUNK)*DIM;
    // prologue: prefetch tile 0 into registers
    float4 kr[4],vr[4];
    #pragma unroll
    for(int gg=0;gg<4;gg++){
      size_t off=kbase+(size_t)(rr+16*gg)*DIM+c4;
      kr[gg]=ld4(Kg+off); vr[gg]=ld4(Vg+off);
    }
    f32x4 acc[4];
    #pragma unroll
    for(int ni=0;ni<4;ni++) acc[ni]=(f32x4){0.f,0.f,0.f,0.f};
    float den_acc[4]={0.f,0.f,0.f,0.f};
    for(int tile=0;tile<8;tile++){
      __syncthreads();   // prev tile's LDS reads done (also covers QL staging on first pass)
      // stage K (scaled, s'-major) and V^T (d-major, s'-contiguous, XOR-swizzled scatter)
      #pragma unroll
      for(int gg=0;gg<4;gg++){
        int r=rr+16*gg;
        float4 kv=kr[gg];
        kv.x*=INV_SCALE; kv.y*=INV_SCALE; kv.z*=INV_SCALE; kv.w*=INV_SCALE;
        uint2 hi,lo; split4(kv,hi,lo);
        *reinterpret_cast<uint2*>(Kth+r*BSTR+c4)=hi;
        *reinterpret_cast<uint2*>(Ktl+r*BSTR+c4)=lo;
        float fv[4]={vr[gg].x,vr[gg].y,vr[gg].z,vr[gg].w};
        #pragma unroll
        for(int e=0;e<4;e++){
          int d=c4+e;
          unsigned short hv=bfh_(fv[e]);
          unsigned short lv=bfl_(fv[e],hv);
          int sp = r ^ (((d>>2)&7)<<3);   // swizzle s' bits 3..5 by d bits 2..4 (store-side)
          VTh[d*BSTR+sp]=hv; VTl[d*BSTR+sp]=lv;
        }
      }
      // issue next tile's global loads (latency hidden under the MFMA phases)
      if(tile<7){
        #pragma unroll
        for(int gg=0;gg<4;gg++){
          size_t off=kbase+(size_t)((tile+1)*64+rr+16*gg)*DIM+c4;
          kr[gg]=ld4(Kg+off); vr[gg]=ld4(Vg+off);
        }
      }
      __syncthreads();
      // ---- logits: D[s'][m] = K_scaled . QL ; wave w owns s' rows 16w..16w+15 ----
      short8 kah[2],kal[2];
      #pragma unroll
      for(int kh=0;kh<2;kh++){
        int ab=(16*w+ln)*BSTR+32*kh+8*g;
        kah[kh]=*reinterpret_cast<const short8*>(Kth+ab);
        kal[kh]=*reinterpret_cast<const short8*>(Ktl+ab);
      }
      #pragma unroll
      for(int ni=0;ni<4;ni++){
        f32x4 dl=(f32x4){0.f,0.f,0.f,0.f};
        #pragma unroll
        for(int kh=0;kh<2;kh++){
          int bb=(16*ni+ln)*BSTR+32*kh+8*g;
          short8 bh=*reinterpret_cast<const short8*>(QLh+bb);
          short8 bl=*reinterpret_cast<const short8*>(QLl+bb);
          dl=MFMA16(kah[kh],bh,dl);
          dl=MFMA16(kah[kh],bl,dl);
          dl=MFMA16(kal[kh],bh,dl);
        }
        // P = exp(logits); D layout: row s' = 16w + 4g + reg, col m = 16ni + ln
        float p0=__expf(dl[0]), p1=__expf(dl[1]), p2=__expf(dl[2]), p3=__expf(dl[3]);
        den_acc[ni]+=p0+p1+p2+p3;
        unsigned short h0=bfh_(p0),h1=bfh_(p1),h2=bfh_(p2),h3=bfh_(p3);
        unsigned short l0=bfl_(p0,h0),l1=bfl_(p1,h1),l2=bfl_(p2,h2),l3=bfl_(p3,h3);
        int pb=(16*ni+ln)*BSTR+16*w+4*g;   // PT[m][s'] s'-contiguous
        *reinterpret_cast<uint2*>(PTh+pb)=make_uint2((unsigned)h0|((unsigned)h1<<16),(unsigned)h2|((unsigned)h3<<16));
        *reinterpret_cast<uint2*>(PTl+pb)=make_uint2((unsigned)l0|((unsigned)l1<<16),(unsigned)l2|((unsigned)l3<<16));
      }
      __syncthreads();
      // ---- PV: acc[m][d] += P^T . V ; wave w owns m rows 16w..16w+15 ----
      short8 pah[2],pal[2];
      #pragma unroll
      for(int kh=0;kh<2;kh++){
        int pb=(16*w+ln)*BSTR+32*kh+8*g;
        pah[kh]=*reinterpret_cast<const short8*>(PTh+pb);
        pal[kh]=*reinterpret_cast<const short8*>(PTl+pb);
      }
      #pragma unroll
      for(int ni=0;ni<4;ni++){
        int row=16*ni+ln;                 // row = d
        int swz=((row>>2)&7)<<3;
        #pragma unroll
        for(int kh=0;kh<2;kh++){
          int vb=row*BSTR+((32*kh+8*g)^swz);   // compensate store-side swizzle
          short8 vh=*reinterpret_cast<const short8*>(VTh+vb);
          short8 vl=*reinterpret_cast<const short8*>(VTl+vb);
          acc[ni]=MFMA16(pah[kh],vh,acc[ni]);
          acc[ni]=MFMA16(pah[kh],vl,acc[ni]);
          acc[ni]=MFMA16(pal[kh],vh,acc[ni]);
        }
      }
    }
    // epilogue: MNUM partials (D layout: row m = 16w+4g+r, col d = 16ni+ln)
    float* num = ws + OFF_MNUM + (size_t)b*4096;
    #pragma unroll
    for(int ni=0;ni<4;ni++){
      #pragma unroll
      for(int r=0;r<4;r++) num[(16*w+4*g+r)*64+16*ni+ln]=acc[ni][r];
      den_acc[ni]+=__shfl_xor(den_acc[ni],16);
      den_acc[ni]+=__shfl_xor(den_acc[ni],32);
    }
    if(lane<16){
      #pragma unroll
      for(int ni=0;ni<4;ni++) sden[w*64+16*ni+lane]=den_acc[ni];
    }
    __syncthreads();
    if(t<64) ws[OFF_MDEN+(size_t)b*64+t]=sden[t]+sden[64+t]+sden[128+t]+sden[192+t];
  }
}

// ---------------- 4. combine partials -> M, then P = W @ M ----------------
__global__ __launch_bounds__(256) void combine_kernel(float* __restrict__ ws){
  __shared__ float sW[64][PAD];
  __shared__ float sM[64][PAD];
  __shared__ float sden[64];
  int h=blockIdx.x, t=threadIdx.x;
  if(t<64){
    float s=0.f;
    for(int c=0;c<NCHUNK;c++) s += ws[OFF_MDEN + ((size_t)h*NCHUNK+c)*64 + t];
    sden[t]=1.0f/s;
  }
  for(int i=t;i<4096;i+=256) sW[i>>6][i&63] = ws[OFF_W + (size_t)h*4096 + i];
  __syncthreads();
  for(int i=t;i<1024;i+=256){
    int m=i>>4, d4=(i&15)*4;
    float sx=0.f,sy=0.f,sz=0.f,sw2=0.f;
    for(int c=0;c<NCHUNK;c++){
      float4 v = ld4(ws + OFF_MNUM + ((size_t)h*NCHUNK+c)*4096 + m*64 + d4);
      sx+=v.x; sy+=v.y; sz+=v.z; sw2+=v.w;
    }
    float iv = sden[m];
    float4 o; o.x=sx*iv; o.y=sy*iv; o.z=sz*iv; o.w=sw2*iv;
    st4(&sM[m][d4], o);
  }
  __syncthreads();
  int i0=(t>>4)*4, j0=(t&15)*4;
  float c[4][4]={};
  mm_tile(c, sW, sM, i0, j0);
  float* P = ws + OFF_P + (size_t)h*4096;
  #pragma unroll
  for(int r=0;r<4;r++){
    float4 o; o.x=c[r][0]; o.y=c[r][1]; o.z=c[r][2]; o.w=c[r][3];
    st4(P + (i0+r)*64 + j0, o);
  }
}

// ---------------- 5. X = rowsoftmax(Q . KL^T) @ P  — MFMA bf16x3 ----------------
// logits computed transposed D[m][s] = KL . Q so the exp'd P stores as PT[s][m] (vectorized);
// P2 prefetched to regs, transpose-scattered into the dead Q slot after matmul1.
// LDS: 2 bf16-pair slots + sden = 37.9 KB -> 4 blocks/CU.
__global__ __launch_bounds__(256) void final_kernel(const float* __restrict__ Qg, float* __restrict__ out, const float* __restrict__ ws){
  __shared__ __align__(16) unsigned char smem[37888];
  int bid=blockIdx.x, t=threadIdx.x;
  int h=bid>>6, s0=(bid&63)*64;
  const int lane=t&63, w=t>>6, ln=lane&15, g=lane>>4;
  const int rr=t>>4, c4=(t&15)*4;
  unsigned short* QBh=(unsigned short*)smem;   // Q rows -> later P2^T rows
  unsigned short* QBl=QBh+4608;
  unsigned short* KLh=QBh+9216;                // KL rows -> later PT[s][m]
  unsigned short* KLl=QBh+13824;
  float* sdenw=(float*)(smem+36864);           // [4][64]
  const float* KL = ws + OFF_KL + (size_t)h*4096;
  const float* P  = ws + OFF_P  + (size_t)h*4096;
  const float* Qb = Qg + ((size_t)h*SEQ + (size_t)s0)*DIM;
  // stage Q (scaled) and KL rows; prefetch P2 into registers
  float4 p2r[4];
  #pragma unroll
  for(int gg=0;gg<4;gg++){
    int row=rr+16*gg;
    p2r[gg]=ld4(P+row*64+c4);
    float4 q=ld4(Qb+(size_t)row*DIM+c4);
    q.x*=INV_SCALE; q.y*=INV_SCALE; q.z*=INV_SCALE; q.w*=INV_SCALE;
    uint2 hi,lo; split4(q,hi,lo);
    *reinterpret_cast<uint2*>(QBh+row*BSTR+c4)=hi;
    *reinterpret_cast<uint2*>(QBl+row*BSTR+c4)=lo;
    float4 kl=ld4(KL+row*64+c4);
    split4(kl,hi,lo);
    *reinterpret_cast<uint2*>(KLh+row*BSTR+c4)=hi;
    *reinterpret_cast<uint2*>(KLl+row*BSTR+c4)=lo;
  }
  __syncthreads();
  // ---- matmul1: D[m][s] = KL . Q^T  (A=KL m-major rows, B=Q s-major rows, k=d) ----
  short8 ah_[2],al_[2];
  #pragma unroll
  for(int kh=0;kh<2;kh++){
    int ab=(16*w+ln)*BSTR+32*kh+8*g;
    ah_[kh]=*reinterpret_cast<const short8*>(KLh+ab);
    al_[kh]=*reinterpret_cast<const short8*>(KLl+ab);
  }
  f32x4 dl[4];
  #pragma unroll
  for(int ni=0;ni<4;ni++){
    f32x4 d=(f32x4){0.f,0.f,0.f,0.f};
    #pragma unroll
    for(int kh=0;kh<2;kh++){
      int bb=(16*ni+ln)*BSTR+32*kh+8*g;
      short8 bh=*reinterpret_cast<const short8*>(QBh+bb);
      short8 bl=*reinterpret_cast<const short8*>(QBl+bb);
      d=MFMA16(ah_[kh],bh,d); d=MFMA16(ah_[kh],bl,d); d=MFMA16(al_[kh],bh,d);
    }
    dl[ni]=d;
  }
  __syncthreads();   // all Q/KL reads done -> slots reusable
  // P2^T scatter into Q slot (rows d, k=m contiguous)
  #pragma unroll
  for(int gg=0;gg<4;gg++){
    int row=rr+16*gg;
    float fp[4]={p2r[gg].x,p2r[gg].y,p2r[gg].z,p2r[gg].w};
    #pragma unroll
    for(int e=0;e<4;e++){
      unsigned short hv=bfh_(fp[e]);
      QBh[(c4+e)*BSTR+row]=hv;
      QBl[(c4+e)*BSTR+row]=bfl_(fp[e],hv);
    }
  }
  // P = exp(D); store PT[s][m] (m contiguous) into KL slot; denominators over m
  float den_acc[4];
  #pragma unroll
  for(int ni=0;ni<4;ni++){
    float p0=__expf(dl[ni][0]), p1=__expf(dl[ni][1]), p2v=__expf(dl[ni][2]), p3v=__expf(dl[ni][3]);
    den_acc[ni]=p0+p1+p2v+p3v;                 // partial over m=16w+4g+{0..3} for s=16ni+ln
    unsigned short h0=bfh_(p0),h1=bfh_(p1),h2=bfh_(p2v),h3=bfh_(p3v);
    unsigned short e0=bfl_(p0,h0),e1=bfl_(p1,h1),e2=bfl_(p2v,h2),e3=bfl_(p3v,h3);
    int pb=(16*ni+ln)*BSTR+16*w+4*g;
    *reinterpret_cast<uint2*>(KLh+pb)=make_uint2((unsigned)h0|((unsigned)h1<<16),(unsigned)h2|((unsigned)h3<<16));
    *reinterpret_cast<uint2*>(KLl+pb)=make_uint2((unsigned)e0|((unsigned)e1<<16),(unsigned)e2|((unsigned)e3<<16));
    den_acc[ni]+=__shfl_xor(den_acc[ni],16);   // reduce over g
    den_acc[ni]+=__shfl_xor(den_acc[ni],32);
  }
  if(lane<16){
    #pragma unroll
    for(int ni=0;ni<4;ni++) sdenw[w*64+16*ni+lane]=den_acc[ni];
  }
  __syncthreads();
  // ---- matmul2: X[s][d] = PT . P2  (A=PT s-major rows, B=P2^T d-major rows, k=m) ----
  #pragma unroll
  for(int kh=0;kh<2;kh++){
    int ab=(16*w+ln)*BSTR+32*kh+8*g;
    ah_[kh]=*reinterpret_cast<const short8*>(KLh+ab);
    al_[kh]=*reinterpret_cast<const short8*>(KLl+ab);
  }
  float inv[4];
  #pragma unroll
  for(int r=0;r<4;r++){
    int s=16*w+4*g+r;
    inv[r]=1.0f/(sdenw[s]+sdenw[64+s]+sdenw[128+s]+sdenw[192+s]);
  }
  #pragma unroll
  for(int ni=0;ni<4;ni++){
    f32x4 d=(f32x4){0.f,0.f,0.f,0.f};
    #pragma unroll
    for(int kh=0;kh<2;kh++){
      int bb=(16*ni+ln)*BSTR+32*kh+8*g;
      short8 bh=*reinterpret_cast<const short8*>(QBh+bb);
      short8 bl=*reinterpret_cast<const short8*>(QBl+bb);
      d=MFMA16(ah_[kh],bh,d); d=MFMA16(ah_[kh],bl,d); d=MFMA16(al_[kh],bh,d);
    }
    #pragma unroll
    for(int r=0;r<4;r++)
      out[((size_t)h*SEQ + (size_t)(s0+16*w+4*g+r))*DIM + 16*ni+ln] = d[r]*inv[r];
  }
}

extern "C" void kernel_launch(void* const* d_in, const int* in_sizes, int n_in,
                              void* d_out, int out_size, void* d_ws, size_t ws_size,
                              hipStream_t stream) {
  const float* Q = (const float*)d_in[0];
  const float* K = (const float*)d_in[1];
  const float* V = (const float*)d_in[2];
  float* out = (float*)d_out;
  float* ws  = (float*)d_ws;

  pool_kernel   <<<BH*32, 256, 0, stream>>>(Q, K, ws);
  k2_kernel     <<<BH,    256, 0, stream>>>(ws);
  fused_kernel  <<<BH + BH*NCHUNK, 256, 0, stream>>>(K, V, ws);
  combine_kernel<<<BH,    256, 0, stream>>>(ws);
  final_kernel  <<<BH*64, 256, 0, stream>>>(Q, out, ws);
}

// Round 8
// 241.920 us; speedup vs baseline: 1.2981x; 1.0091x over previous
//
#include <hip/hip_runtime.h>
#include <cstdint>

#define BH 48
#define SEQ 4096
#define DIM 64
#define SEG 64
#define NCHUNK 16
#define CHUNK 256
#define PAD 68
#define BSTR 72   // bf16 row stride in ushorts (144 B = 16B-aligned)

static constexpr float INV_SCALE = 0.35355339059327379f; // 1/sqrt(sqrt(64))

// workspace float offsets
#define OFF_QL   0u         // 48*4096
#define OFF_KL   196608u    // 48*4096
#define OFF_K2   393216u    // 48*4096
#define OFF_W    589824u    // 48*4096
#define OFF_P    786432u    // 48*4096
#define OFF_MNUM 983040u    // 48*16*4096 = 3145728
#define OFF_MDEN 4128768u   // 48*16*64  = 49152
#define OFF_CMAX 4177920u   // 48
#define OFF_RMAX 4177968u   // 48   (total 4178016 floats ~ 16.7 MB)

typedef __attribute__((ext_vector_type(8))) short short8;
typedef __attribute__((ext_vector_type(4))) float f32x4;
#define MFMA16(a,b,c) __builtin_amdgcn_mfma_f32_16x16x32_bf16(a,b,c,0,0,0)

__device__ __forceinline__ float4 ld4(const float* p){ return *reinterpret_cast<const float4*>(p); }
__device__ __forceinline__ void st4(float* p, float4 v){ *reinterpret_cast<float4*>(p) = v; }

// bf16 high part (round-to-nearest-even) and low residual part
__device__ __forceinline__ unsigned short bfh_(float x){
  unsigned u = __float_as_uint(x);
  return (unsigned short)((u + 0x7fffu + ((u>>16)&1u)) >> 16);
}
__device__ __forceinline__ unsigned short bfl_(float x, unsigned short h){
  float r = x - __uint_as_float(((unsigned)h)<<16);
  return (unsigned short)(__float_as_uint(r) >> 16);   // truncate; residual-of-residual ~2^-17
}
__device__ __forceinline__ void split4(float4 v, uint2& hi, uint2& lo){
  unsigned short h0=bfh_(v.x), h1=bfh_(v.y), h2=bfh_(v.z), h3=bfh_(v.w);
  unsigned short l0=bfl_(v.x,h0), l1=bfl_(v.y,h1), l2=bfl_(v.z,h2), l3=bfl_(v.w,h3);
  hi = make_uint2((unsigned)h0 | ((unsigned)h1<<16), (unsigned)h2 | ((unsigned)h3<<16));
  lo = make_uint2((unsigned)l0 | ((unsigned)l1<<16), (unsigned)l2 | ((unsigned)l3<<16));
}
__device__ __forceinline__ short8 mk8(uint2 a, uint2 b){
  union { short8 s; uint4 u; } x; x.u = make_uint4(a.x,a.y,b.x,b.y); return x.s;
}

// C[4][4] += A[i0..i0+3][:] * B[:][j0..j0+3], 64-deep, LDS operands (pad=68 keeps 16B align)
__device__ __forceinline__ void mm_tile(float c[4][4], const float (*A)[PAD], const float (*B)[PAD], int i0, int j0){
  #pragma unroll 4
  for(int k=0;k<64;k+=4){
    float4 a4[4];
    #pragma unroll
    for(int r=0;r<4;r++) a4[r] = ld4(&A[i0+r][k]);
    #pragma unroll
    for(int kk=0;kk<4;kk++){
      float4 bv = ld4(&B[k+kk][j0]);
      #pragma unroll
      for(int r=0;r<4;r++){
        float a = ((const float*)&a4[r])[kk];
        c[r][0] += a*bv.x; c[r][1] += a*bv.y; c[r][2] += a*bv.z; c[r][3] += a*bv.w;
      }
    }
  }
}

// same, but A rows come straight from global (row-major, stride 64) — L2-resident broadcast reads
__device__ __forceinline__ void mm_tile_gA(float c[4][4], const float* __restrict__ gA, const float (*B)[PAD], int i0, int j0){
  #pragma unroll 4
  for(int k=0;k<64;k+=4){
    float4 a4[4];
    #pragma unroll
    for(int r=0;r<4;r++) a4[r] = ld4(gA + (i0+r)*64 + k);
    #pragma unroll
    for(int kk=0;kk<4;kk++){
      float4 bv = ld4(&B[k+kk][j0]);
      #pragma unroll
      for(int r=0;r<4;r++){
        float a = ((const float*)&a4[r])[kk];
        c[r][0] += a*bv.x; c[r][1] += a*bv.y; c[r][2] += a*bv.z; c[r][3] += a*bv.w;
      }
    }
  }
}

// C[4][4] += A * (dg*I - B)   (Newton-Schulz steps)
__device__ __forceinline__ void mm_tile_diag(float c[4][4], const float (*A)[PAD], const float (*B)[PAD], int i0, int j0, float dg){
  #pragma unroll 4
  for(int k=0;k<64;k+=4){
    float4 a4[4];
    #pragma unroll
    for(int r=0;r<4;r++) a4[r] = ld4(&A[i0+r][k]);
    #pragma unroll
    for(int kk=0;kk<4;kk++){
      float4 bv = ld4(&B[k+kk][j0]);
      float b0=-bv.x, b1=-bv.y, b2=-bv.z, b3=-bv.w;
      int dd = k+kk-j0;
      if(dd==0) b0+=dg; else if(dd==1) b1+=dg; else if(dd==2) b2+=dg; else if(dd==3) b3+=dg;
      #pragma unroll
      for(int r=0;r<4;r++){
        float a = ((const float*)&a4[r])[kk];
        c[r][0]+=a*b0; c[r][1]+=a*b1; c[r][2]+=a*b2; c[r][3]+=a*b3;
      }
    }
  }
}

// ---------------- 1. landmark pooling (reads Q,K once; writes scaled QL,KL) ----------------
__global__ __launch_bounds__(256) void pool_kernel(const float* __restrict__ Qg, const float* __restrict__ Kg, float* __restrict__ ws){
  int bx = blockIdx.x;              // 48 heads * 2 tensors * 16 landmark-groups = 1536
  int head = bx >> 5;
  int rest = bx & 31;
  int tensor = rest >> 4;           // 0:Q 1:K
  int l0 = (rest & 15) * 4;
  int t = threadIdx.x;
  int ll = t >> 6;                  // wave id -> local landmark
  int lane = t & 63;
  int d4 = (lane & 15) * 4;
  int rq = lane >> 4;               // row phase 0..3
  const float* src = tensor ? Kg : Qg;
  float* dst = ws + (tensor ? OFF_KL : OFF_QL);
  int l = l0 + ll;
  const float* base = src + ((size_t)head*SEQ + (size_t)l*SEG)*DIM + d4;
  float sx=0.f, sy=0.f, sz=0.f, sw=0.f;
  #pragma unroll 4
  for(int r=rq; r<SEG; r+=4){
    float4 v = ld4(base + (size_t)r*DIM);
    sx+=v.x; sy+=v.y; sz+=v.z; sw+=v.w;
  }
  sx += __shfl_xor(sx,16); sy += __shfl_xor(sy,16); sz += __shfl_xor(sz,16); sw += __shfl_xor(sw,16);
  sx += __shfl_xor(sx,32); sy += __shfl_xor(sy,32); sz += __shfl_xor(sz,32); sw += __shfl_xor(sw,32);
  if(rq==0){
    const float sc = INV_SCALE / 64.0f;
    float4 o; o.x=sx*sc; o.y=sy*sc; o.z=sz*sc; o.w=sw*sc;
    st4(dst + ((size_t)head*64 + l)*DIM + d4, o);
  }
}

// ---------------- 2. kernel_2 softmax + per-head L1 row/col max ----------------
__global__ __launch_bounds__(256) void k2_kernel(float* __restrict__ ws){
  __shared__ float sQ[64][65];
  __shared__ float sK[64][65];
  __shared__ float sE[64][65];
  __shared__ float red[128];
  int h = blockIdx.x, t = threadIdx.x;
  const float* QL = ws + OFF_QL + (size_t)h*4096;
  const float* KL = ws + OFF_KL + (size_t)h*4096;
  for(int i=t;i<4096;i+=256){ sQ[i>>6][i&63]=QL[i]; sK[i>>6][i&63]=KL[i]; }
  __syncthreads();
  int i = t>>2, q = t&3;
  float l[16];
  #pragma unroll
  for(int jj=0;jj<16;jj++){
    int j = q*16+jj;
    float s=0.f;
    for(int d=0;d<64;d++) s += sQ[i][d]*sK[j][d];
    l[jj]=s;
  }
  float mx = l[0];
  #pragma unroll
  for(int jj=1;jj<16;jj++) mx = fmaxf(mx,l[jj]);
  mx = fmaxf(mx, __shfl_xor(mx,1));
  mx = fmaxf(mx, __shfl_xor(mx,2));
  float sum=0.f;
  #pragma unroll
  for(int jj=0;jj<16;jj++){ l[jj]=__expf(l[jj]-mx); sum+=l[jj]; }
  sum += __shfl_xor(sum,1);
  sum += __shfl_xor(sum,2);
  float inv = 1.0f/sum;
  #pragma unroll
  for(int jj=0;jj<16;jj++) sE[i][q*16+jj] = l[jj]*inv;
  __syncthreads();
  float* K2 = ws + OFF_K2 + (size_t)h*4096;
  for(int idx=t; idx<4096; idx+=256) K2[idx] = sE[idx>>6][idx&63];
  if(t<64){
    float cs=0.f, rs=0.f;
    for(int r=0;r<64;r++){ cs += sE[r][t]; rs += sE[t][r]; }
    red[t]=cs; red[64+t]=rs;
  }
  __syncthreads();
  if(t==0){
    float cm=0.f, rm=0.f;
    for(int j=0;j<64;j++){ cm=fmaxf(cm,red[j]); rm=fmaxf(rm,red[64+j]); }
    ws[OFF_CMAX+h]=cm; ws[OFF_RMAX+h]=rm;
  }
}

// ---------------- 3. fused: Newton-Schulz (blocks 0..47, MFMA bf16x3 + fp32 last iter) ||
//                  kernel_3@V partials (blocks 48..815, MFMA bf16x3, CHUNK=256) ----------------
__global__ __launch_bounds__(256) void fused_kernel(const float* __restrict__ Kg, const float* __restrict__ Vg, float* __restrict__ ws){
  __shared__ __align__(16) unsigned char smem[74752];
  __shared__ float sscale;
  int bid = blockIdx.x, t = threadIdx.x;
  const int lane=t&63, w=t>>6, ln=lane&15, g=lane>>4;
  const int rr=t>>4, c4=(t&15)*4;
  if(bid < BH){
    // ---- Newton-Schulz pseudo-inverse of kernel_2, head=bid (unchanged from round 5) ----
    int h = bid;
    const float* K2 = ws + OFF_K2 + (size_t)h*4096;
    unsigned short* Uh=(unsigned short*)smem;
    unsigned short* Ul=Uh+4608;
    unsigned short* Rh=Uh+9216;
    unsigned short* Rl=Uh+13824;
    unsigned short* Ch=Uh+18432;
    unsigned short* Cl=Uh+23040;
    unsigned short* Gh=Uh+27648;
    unsigned short* Gl=Uh+32256;
    // Km A-frags from global K2 (row 16w+ln, k=32kh+8g+e), unscaled
    short8 kmh[2],kml[2];
    #pragma unroll
    for(int kh=0;kh<2;kh++){
      const float* p=K2+(16*w+ln)*64+32*kh+8*g;
      float4 x0=ld4(p), x1=ld4(p+4);
      uint2 h0,l0,h1,l1; split4(x0,h0,l0); split4(x1,h1,l1);
      kmh[kh]=mk8(h0,h1); kml[kh]=mk8(l0,l1);
    }
    // global scale = 1/(max col-L1 * max row-L1) over all heads — wave-parallel reduce
    if(t<64){
      float cm=(lane<BH)?ws[OFF_CMAX+lane]:0.f;
      float rm=(lane<BH)?ws[OFF_RMAX+lane]:0.f;
      #pragma unroll
      for(int s=32;s>=1;s>>=1){ cm=fmaxf(cm,__shfl_xor(cm,s)); rm=fmaxf(rm,__shfl_xor(rm,s)); }
      if(t==0) sscale=1.0f/(cm*rm);
    }
    __syncthreads();
    float scale=sscale;
    // stage U0 = scale*Km (rows) ; R0 = scale*Km^T (transpose scatter)
    #pragma unroll
    for(int gg=0;gg<4;gg++){
      int m=rr+16*gg;
      float4 v=ld4(K2+m*64+c4);
      v.x*=scale; v.y*=scale; v.z*=scale; v.w*=scale;
      uint2 hi,lo; split4(v,hi,lo);
      *reinterpret_cast<uint2*>(Uh+m*BSTR+c4)=hi;
      *reinterpret_cast<uint2*>(Ul+m*BSTR+c4)=lo;
      float fv[4]={v.x,v.y,v.z,v.w};
      #pragma unroll
      for(int e=0;e<4;e++){
        unsigned short hv=bfh_(fv[e]);
        Rh[(c4+e)*BSTR+m]=hv;
        Rl[(c4+e)*BSTR+m]=bfl_(fv[e],hv);
      }
    }
    __syncthreads();
    f32x4 dA[4];
    short8 ah[2],al[2];
    for(int it=0; it<5; it++){
      // ---- S1: KV = Km @ Vm  (B-frag rows from U = Vm^T) ----
      #pragma unroll
      for(int ni=0;ni<4;ni++){
        f32x4 d=(f32x4){0.f,0.f,0.f,0.f};
        #pragma unroll
        for(int kh=0;kh<2;kh++){
          int bb=(16*ni+ln)*BSTR+32*kh+8*g;
          short8 bh=*reinterpret_cast<const short8*>(Uh+bb);
          short8 bl=*reinterpret_cast<const short8*>(Ul+bb);
          d=MFMA16(kmh[kh],bh,d); d=MFMA16(kmh[kh],bl,d); d=MFMA16(kml[kh],bh,d);
        }
        dA[ni]=d;
      }
      // write KV row-major (C slot) and G7=(7I-KV)^T (G slot)
      #pragma unroll
      for(int ni=0;ni<4;ni++){
        int j=16*ni+ln;
        float4 tv; float* pv=(float*)&tv;
        #pragma unroll
        for(int r=0;r<4;r++){
          float v=dA[ni][r];
          int i=16*w+4*g+r;
          unsigned short hv=bfh_(v);
          Ch[i*BSTR+j]=hv; Cl[i*BSTR+j]=bfl_(v,hv);
          pv[r]=((i==j)?7.0f:0.0f)-v;
        }
        uint2 hi,lo; split4(tv,hi,lo);
        *reinterpret_cast<uint2*>(Gh+j*BSTR+16*w+4*g)=hi;
        *reinterpret_cast<uint2*>(Gl+j*BSTR+16*w+4*g)=lo;
      }
      __syncthreads();
      // ---- S2: B2 = KV @ (7I-KV) ; cache KV A-frags for S3 ----
      #pragma unroll
      for(int kh=0;kh<2;kh++){
        int ab=(16*w+ln)*BSTR+32*kh+8*g;
        ah[kh]=*reinterpret_cast<const short8*>(Ch+ab);
        al[kh]=*reinterpret_cast<const short8*>(Cl+ab);
      }
      #pragma unroll
      for(int ni=0;ni<4;ni++){
        f32x4 d=(f32x4){0.f,0.f,0.f,0.f};
        #pragma unroll
        for(int kh=0;kh<2;kh++){
          int bb=(16*ni+ln)*BSTR+32*kh+8*g;
          short8 bh=*reinterpret_cast<const short8*>(Gh+bb);
          short8 bl=*reinterpret_cast<const short8*>(Gl+bb);
          d=MFMA16(ah[kh],bh,d); d=MFMA16(ah[kh],bl,d); d=MFMA16(al[kh],bh,d);
        }
        dA[ni]=d;
      }
      __syncthreads();
      // write G15=(15I-B2)^T into G slot
      #pragma unroll
      for(int ni=0;ni<4;ni++){
        int j=16*ni+ln;
        float4 tv; float* pv=(float*)&tv;
        #pragma unroll
        for(int r=0;r<4;r++){ int i=16*w+4*g+r; pv[r]=((i==j)?15.0f:0.0f)-dA[ni][r]; }
        uint2 hi,lo; split4(tv,hi,lo);
        *reinterpret_cast<uint2*>(Gh+j*BSTR+16*w+4*g)=hi;
        *reinterpret_cast<uint2*>(Gl+j*BSTR+16*w+4*g)=lo;
      }
      __syncthreads();
      // ---- S3: B1' = KV @ (15I-B2)  (A cached) ----
      #pragma unroll
      for(int ni=0;ni<4;ni++){
        f32x4 d=(f32x4){0.f,0.f,0.f,0.f};
        #pragma unroll
        for(int kh=0;kh<2;kh++){
          int bb=(16*ni+ln)*BSTR+32*kh+8*g;
          short8 bh=*reinterpret_cast<const short8*>(Gh+bb);
          short8 bl=*reinterpret_cast<const short8*>(Gl+bb);
          d=MFMA16(ah[kh],bh,d); d=MFMA16(ah[kh],bl,d); d=MFMA16(al[kh],bh,d);
        }
        dA[ni]=d;
      }
      __syncthreads();
      // write G13=(13I-B1')^T into C slot (KV dead)
      #pragma unroll
      for(int ni=0;ni<4;ni++){
        int j=16*ni+ln;
        float4 tv; float* pv=(float*)&tv;
        #pragma unroll
        for(int r=0;r<4;r++){ int i=16*w+4*g+r; pv[r]=((i==j)?13.0f:0.0f)-dA[ni][r]; }
        uint2 hi,lo; split4(tv,hi,lo);
        *reinterpret_cast<uint2*>(Ch+j*BSTR+16*w+4*g)=hi;
        *reinterpret_cast<uint2*>(Cl+j*BSTR+16*w+4*g)=lo;
      }
      __syncthreads();
      // ---- S4: Vm' = 0.25 * Vm @ (13I-B1')  (A from R rows, B from C slot) ----
      #pragma unroll
      for(int kh=0;kh<2;kh++){
        int ab=(16*w+ln)*BSTR+32*kh+8*g;
        ah[kh]=*reinterpret_cast<const short8*>(Rh+ab);
        al[kh]=*reinterpret_cast<const short8*>(Rl+ab);
      }
      #pragma unroll
      for(int ni=0;ni<4;ni++){
        f32x4 d=(f32x4){0.f,0.f,0.f,0.f};
        #pragma unroll
        for(int kh=0;kh<2;kh++){
          int bb=(16*ni+ln)*BSTR+32*kh+8*g;
          short8 bh=*reinterpret_cast<const short8*>(Ch+bb);
          short8 bl=*reinterpret_cast<const short8*>(Cl+bb);
          d=MFMA16(ah[kh],bh,d); d=MFMA16(ah[kh],bl,d); d=MFMA16(al[kh],bh,d);
        }
        dA[ni]=d;
      }
      __syncthreads();
      // write R' row-major + U'=Vm'^T
      #pragma unroll
      for(int ni=0;ni<4;ni++){
        int j=16*ni+ln;
        float4 tv; float* pv=(float*)&tv;
        #pragma unroll
        for(int r=0;r<4;r++){
          float v=0.25f*dA[ni][r];
          int i=16*w+4*g+r;
          unsigned short hv=bfh_(v);
          Rh[i*BSTR+j]=hv; Rl[i*BSTR+j]=bfl_(v,hv);
          pv[r]=v;
        }
        uint2 hi,lo; split4(tv,hi,lo);
        *reinterpret_cast<uint2*>(Uh+j*BSTR+16*w+4*g)=hi;
        *reinterpret_cast<uint2*>(Ul+j*BSTR+16*w+4*g)=lo;
      }
      __syncthreads();
    }
    // ---- final (6th) iteration in fp32 for output precision ----
    float (*Vmf)[PAD]=(float(*)[PAD])(smem+36864);   // overlays C slot (dead)
    for(int i=t;i<4096;i+=256){
      int r_=i>>6, c_=i&63;
      float v=__uint_as_float(((unsigned)Rh[r_*BSTR+c_])<<16)
             +__uint_as_float(((unsigned)Rl[r_*BSTR+c_])<<16);
      Vmf[r_][c_]=v;
    }
    __syncthreads();
    float (*B1)[PAD]=(float(*)[PAD])(smem);          // overlays U slot (dead)
    float (*B2)[PAD]=(float(*)[PAD])(smem+17408);    // overlays R slot (dead after Vmf build)
    int i0=(t>>4)*4, j0=(t&15)*4;
    { // B1 = Km @ Vm   (A rows from global K2, L2-hot)
      float c[4][4]={};
      mm_tile_gA(c,K2,Vmf,i0,j0);
      #pragma unroll
      for(int r=0;r<4;r++){ float4 o; o.x=c[r][0];o.y=c[r][1];o.z=c[r][2];o.w=c[r][3]; st4(&B1[i0+r][j0],o); }
      __syncthreads();
    }
    { // B2 = KV @ (7I - KV)
      float c[4][4]={};
      mm_tile_diag(c,B1,B1,i0,j0,7.0f);
      #pragma unroll
      for(int r=0;r<4;r++){ float4 o; o.x=c[r][0];o.y=c[r][1];o.z=c[r][2];o.w=c[r][3]; st4(&B2[i0+r][j0],o); }
      __syncthreads();
    }
    { // B1 = KV @ (15I - B2)   (in-place)
      float c[4][4]={};
      mm_tile_diag(c,B1,B2,i0,j0,15.0f);
      __syncthreads();
      #pragma unroll
      for(int r=0;r<4;r++){ float4 o; o.x=c[r][0];o.y=c[r][1];o.z=c[r][2];o.w=c[r][3]; st4(&B1[i0+r][j0],o); }
      __syncthreads();
    }
    { // Vm = 0.25 * Vm @ (13I - B1)   (in-place)
      float c[4][4]={};
      mm_tile_diag(c,Vmf,B1,i0,j0,13.0f);
      __syncthreads();
      #pragma unroll
      for(int r=0;r<4;r++){ float4 o; o.x=0.25f*c[r][0];o.y=0.25f*c[r][1];o.z=0.25f*c[r][2];o.w=0.25f*c[r][3]; st4(&Vmf[i0+r][j0],o); }
      __syncthreads();
    }
    float* W = ws + OFF_W + (size_t)h*4096;
    for(int i=t;i<4096;i+=256) W[i] = Vmf[i>>6][i&63];
  } else {
    // ---- kernel_3 @ V partial via MFMA bf16x3: block = (head, 256-key chunk) ----
    int b = bid - BH;
    int h = b >> 4, ch = b & 15;
    unsigned short* QLh=(unsigned short*)smem;   // each array 64*BSTR ushorts = 9216 B
    unsigned short* QLl=QLh+4608;
    unsigned short* Kth=QLh+9216;
    unsigned short* Ktl=QLh+13824;
    unsigned short* VTh=QLh+18432;
    unsigned short* VTl=QLh+23040;
    unsigned short* PTh=QLh+27648;
    unsigned short* PTl=QLh+32256;
    float* sden=(float*)(smem+73728);            // [4][64]
    const int va=t&15, vb=t>>4;                  // V staging: 4x4 tile at rows 4va.., cols 4vb..
    const float* QL = ws + OFF_QL + (size_t)h*4096;
    // stage QL (hi/lo bf16, m-major rows, k=d contiguous)
    #pragma unroll
    for(int gg=0;gg<4;gg++){
      int m=rr+16*gg;
      float4 v=ld4(QL+m*64+c4);
      uint2 hi,lo; split4(v,hi,lo);
      *reinterpret_cast<uint2*>(QLh+m*BSTR+c4)=hi;
      *reinterpret_cast<uint2*>(QLl+m*BSTR+c4)=lo;
    }
    const size_t kbase=((size_t)h*SEQ+(size_t)ch*CHUNK)*DIM;
    // prologue: prefetch tile 0 into registers (K rows rr+16gg; V 4x4 tile rows 4va+i col 4vb)
    float4 kr[4],vr[4];
    #pragma unroll
    for(int gg=0;gg<4;gg++){
      kr[gg]=ld4(Kg+kbase+(size_t)(rr+16*gg)*DIM+c4);
      vr[gg]=ld4(Vg+kbase+(size_t)(4*va+gg)*DIM+4*vb);
    }
    f32x4 acc[4];
    #pragma unroll
    for(int ni=0;ni<4;ni++) acc[ni]=(f32x4){0.f,0.f,0.f,0.f};
    float den_acc[4]={0.f,0.f,0.f,0.f};
    for(int tile=0;tile<CHUNK/64;tile++){
      __syncthreads();   // prev tile's LDS reads done (also covers QL staging on first pass)
      // stage K (scaled, s'-major, uint2)
      #pragma unroll
      for(int gg=0;gg<4;gg++){
        int r=rr+16*gg;
        float4 kv=kr[gg];
        kv.x*=INV_SCALE; kv.y*=INV_SCALE; kv.z*=INV_SCALE; kv.w*=INV_SCALE;
        uint2 hi,lo; split4(kv,hi,lo);
        *reinterpret_cast<uint2*>(Kth+r*BSTR+c4)=hi;
        *reinterpret_cast<uint2*>(Ktl+r*BSTR+c4)=lo;
      }
      // stage V^T via in-register 4x4 transpose: VT[4vb+j][4va..4va+3] as uint2 (no scalar scatter)
      #pragma unroll
      for(int j=0;j<4;j++){
        float e0=((const float*)&vr[0])[j], e1=((const float*)&vr[1])[j];
        float e2=((const float*)&vr[2])[j], e3=((const float*)&vr[3])[j];
        unsigned short h0=bfh_(e0),h1=bfh_(e1),h2=bfh_(e2),h3=bfh_(e3);
        unsigned short l0=bfl_(e0,h0),l1=bfl_(e1,h1),l2=bfl_(e2,h2),l3=bfl_(e3,h3);
        int vo=(4*vb+j)*BSTR+4*va;
        *reinterpret_cast<uint2*>(VTh+vo)=make_uint2((unsigned)h0|((unsigned)h1<<16),(unsigned)h2|((unsigned)h3<<16));
        *reinterpret_cast<uint2*>(VTl+vo)=make_uint2((unsigned)l0|((unsigned)l1<<16),(unsigned)l2|((unsigned)l3<<16));
      }
      // issue next tile's global loads (latency hidden under the MFMA phases)
      if(tile<CHUNK/64-1){
        #pragma unroll
        for(int gg=0;gg<4;gg++){
          kr[gg]=ld4(Kg+kbase+(size_t)((tile+1)*64+rr+16*gg)*DIM+c4);
          vr[gg]=ld4(Vg+kbase+(size_t)((tile+1)*64+4*va+gg)*DIM+4*vb);
        }
      }
      __syncthreads();
      // ---- logits: D[s'][m] = K_scaled . QL ; wave w owns s' rows 16w..16w+15 ----
      short8 kah[2],kal[2];
      #pragma unroll
      for(int kh=0;kh<2;kh++){
        int ab=(16*w+ln)*BSTR+32*kh+8*g;
        kah[kh]=*reinterpret_cast<const short8*>(Kth+ab);
        kal[kh]=*reinterpret_cast<const short8*>(Ktl+ab);
      }
      #pragma unroll
      for(int ni=0;ni<4;ni++){
        f32x4 dl=(f32x4){0.f,0.f,0.f,0.f};
        #pragma unroll
        for(int kh=0;kh<2;kh++){
          int bb=(16*ni+ln)*BSTR+32*kh+8*g;
          short8 bh=*reinterpret_cast<const short8*>(QLh+bb);
          short8 bl=*reinterpret_cast<const short8*>(QLl+bb);
          dl=MFMA16(kah[kh],bh,dl);
          dl=MFMA16(kah[kh],bl,dl);
          dl=MFMA16(kal[kh],bh,dl);
        }
        // P = exp(logits); D layout: row s' = 16w + 4g + reg, col m = 16ni + ln
        float p0=__expf(dl[0]), p1=__expf(dl[1]), p2=__expf(dl[2]), p3=__expf(dl[3]);
        den_acc[ni]+=p0+p1+p2+p3;
        unsigned short h0=bfh_(p0),h1=bfh_(p1),h2=bfh_(p2),h3=bfh_(p3);
        unsigned short l0=bfl_(p0,h0),l1=bfl_(p1,h1),l2=bfl_(p2,h2),l3=bfl_(p3,h3);
        int pb=(16*ni+ln)*BSTR+16*w+4*g;   // PT[m][s'] s'-contiguous
        *reinterpret_cast<uint2*>(PTh+pb)=make_uint2((unsigned)h0|((unsigned)h1<<16),(unsigned)h2|((unsigned)h3<<16));
        *reinterpret_cast<uint2*>(PTl+pb)=make_uint2((unsigned)l0|((unsigned)l1<<16),(unsigned)l2|((unsigned)l3<<16));
      }
      __syncthreads();
      // ---- PV: acc[m][d] += P^T . V ; wave w owns m rows 16w..16w+15 ----
      short8 pah[2],pal[2];
      #pragma unroll
      for(int kh=0;kh<2;kh++){
        int pb=(16*w+ln)*BSTR+32*kh+8*g;
        pah[kh]=*reinterpret_cast<const short8*>(PTh+pb);
        pal[kh]=*reinterpret_cast<const short8*>(PTl+pb);
      }
      #pragma unroll
      for(int ni=0;ni<4;ni++){
        int row=16*ni+ln;                 // row = d
        #pragma unroll
        for(int kh=0;kh<2;kh++){
          int vo=row*BSTR+32*kh+8*g;
          short8 vh=*reinterpret_cast<const short8*>(VTh+vo);
          short8 vl=*reinterpret_cast<const short8*>(VTl+vo);
          acc[ni]=MFMA16(pah[kh],vh,acc[ni]);
          acc[ni]=MFMA16(pah[kh],vl,acc[ni]);
          acc[ni]=MFMA16(pal[kh],vh,acc[ni]);
        }
      }
    }
    // epilogue: MNUM partials (D layout: row m = 16w+4g+r, col d = 16ni+ln)
    float* num = ws + OFF_MNUM + (size_t)b*4096;
    #pragma unroll
    for(int ni=0;ni<4;ni++){
      #pragma unroll
      for(int r=0;r<4;r++) num[(16*w+4*g+r)*64+16*ni+ln]=acc[ni][r];
      den_acc[ni]+=__shfl_xor(den_acc[ni],16);
      den_acc[ni]+=__shfl_xor(den_acc[ni],32);
    }
    if(lane<16){
      #pragma unroll
      for(int ni=0;ni<4;ni++) sden[w*64+16*ni+lane]=den_acc[ni];
    }
    __syncthreads();
    if(t<64) ws[OFF_MDEN+(size_t)b*64+t]=sden[t]+sden[64+t]+sden[128+t]+sden[192+t];
  }
}

// ---------------- 4. combine partials -> M, then P = W @ M ----------------
__global__ __launch_bounds__(256) void combine_kernel(float* __restrict__ ws){
  __shared__ float sW[64][PAD];
  __shared__ float sM[64][PAD];
  __shared__ float sden[64];
  int h=blockIdx.x, t=threadIdx.x;
  if(t<64){
    float s=0.f;
    for(int c=0;c<NCHUNK;c++) s += ws[OFF_MDEN + ((size_t)h*NCHUNK+c)*64 + t];
    sden[t]=1.0f/s;
  }
  for(int i=t;i<4096;i+=256) sW[i>>6][i&63] = ws[OFF_W + (size_t)h*4096 + i];
  __syncthreads();
  for(int i=t;i<1024;i+=256){
    int m=i>>4, d4=(i&15)*4;
    float sx=0.f,sy=0.f,sz=0.f,sw2=0.f;
    for(int c=0;c<NCHUNK;c++){
      float4 v = ld4(ws + OFF_MNUM + ((size_t)h*NCHUNK+c)*4096 + m*64 + d4);
      sx+=v.x; sy+=v.y; sz+=v.z; sw2+=v.w;
    }
    float iv = sden[m];
    float4 o; o.x=sx*iv; o.y=sy*iv; o.z=sz*iv; o.w=sw2*iv;
    st4(&sM[m][d4], o);
  }
  __syncthreads();
  int i0=(t>>4)*4, j0=(t&15)*4;
  float c[4][4]={};
  mm_tile(c, sW, sM, i0, j0);
  float* P = ws + OFF_P + (size_t)h*4096;
  #pragma unroll
  for(int r=0;r<4;r++){
    float4 o; o.x=c[r][0]; o.y=c[r][1]; o.z=c[r][2]; o.w=c[r][3];
    st4(P + (i0+r)*64 + j0, o);
  }
}

// ---------------- 5. X = rowsoftmax(Q . KL^T) @ P  — MFMA bf16x3 (unchanged from round 6) ----------------
__global__ __launch_bounds__(256) void final_kernel(const float* __restrict__ Qg, float* __restrict__ out, const float* __restrict__ ws){
  __shared__ __align__(16) unsigned char smem[37888];
  int bid=blockIdx.x, t=threadIdx.x;
  int h=bid>>6, s0=(bid&63)*64;
  const int lane=t&63, w=t>>6, ln=lane&15, g=lane>>4;
  const int rr=t>>4, c4=(t&15)*4;
  unsigned short* QBh=(unsigned short*)smem;   // Q rows -> later P2^T rows
  unsigned short* QBl=QBh+4608;
  unsigned short* KLh=QBh+9216;                // KL rows -> later PT[s][m]
  unsigned short* KLl=QBh+13824;
  float* sdenw=(float*)(smem+36864);           // [4][64]
  const float* KL = ws + OFF_KL + (size_t)h*4096;
  const float* P  = ws + OFF_P  + (size_t)h*4096;
  const float* Qb = Qg + ((size_t)h*SEQ + (size_t)s0)*DIM;
  // stage Q (scaled) and KL rows; prefetch P2 into registers
  float4 p2r[4];
  #pragma unroll
  for(int gg=0;gg<4;gg++){
    int row=rr+16*gg;
    p2r[gg]=ld4(P+row*64+c4);
    float4 q=ld4(Qb+(size_t)row*DIM+c4);
    q.x*=INV_SCALE; q.y*=INV_SCALE; q.z*=INV_SCALE; q.w*=INV_SCALE;
    uint2 hi,lo; split4(q,hi,lo);
    *reinterpret_cast<uint2*>(QBh+row*BSTR+c4)=hi;
    *reinterpret_cast<uint2*>(QBl+row*BSTR+c4)=lo;
    float4 kl=ld4(KL+row*64+c4);
    split4(kl,hi,lo);
    *reinterpret_cast<uint2*>(KLh+row*BSTR+c4)=hi;
    *reinterpret_cast<uint2*>(KLl+row*BSTR+c4)=lo;
  }
  __syncthreads();
  // ---- matmul1: D[m][s] = KL . Q^T  (A=KL m-major rows, B=Q s-major rows, k=d) ----
  short8 ah_[2],al_[2];
  #pragma unroll
  for(int kh=0;kh<2;kh++){
    int ab=(16*w+ln)*BSTR+32*kh+8*g;
    ah_[kh]=*reinterpret_cast<const short8*>(KLh+ab);
    al_[kh]=*reinterpret_cast<const short8*>(KLl+ab);
  }
  f32x4 dl[4];
  #pragma unroll
  for(int ni=0;ni<4;ni++){
    f32x4 d=(f32x4){0.f,0.f,0.f,0.f};
    #pragma unroll
    for(int kh=0;kh<2;kh++){
      int bb=(16*ni+ln)*BSTR+32*kh+8*g;
      short8 bh=*reinterpret_cast<const short8*>(QBh+bb);
      short8 bl=*reinterpret_cast<const short8*>(QBl+bb);
      d=MFMA16(ah_[kh],bh,d); d=MFMA16(ah_[kh],bl,d); d=MFMA16(al_[kh],bh,d);
    }
    dl[ni]=d;
  }
  __syncthreads();   // all Q/KL reads done -> slots reusable
  // P2^T scatter into Q slot (rows d, k=m contiguous)
  #pragma unroll
  for(int gg=0;gg<4;gg++){
    int row=rr+16*gg;
    float fp[4]={p2r[gg].x,p2r[gg].y,p2r[gg].z,p2r[gg].w};
    #pragma unroll
    for(int e=0;e<4;e++){
      unsigned short hv=bfh_(fp[e]);
      QBh[(c4+e)*BSTR+row]=hv;
      QBl[(c4+e)*BSTR+row]=bfl_(fp[e],hv);
    }
  }
  // P = exp(D); store PT[s][m] (m contiguous) into KL slot; denominators over m
  float den_acc[4];
  #pragma unroll
  for(int ni=0;ni<4;ni++){
    float p0=__expf(dl[ni][0]), p1=__expf(dl[ni][1]), p2v=__expf(dl[ni][2]), p3v=__expf(dl[ni][3]);
    den_acc[ni]=p0+p1+p2v+p3v;                 // partial over m=16w+4g+{0..3} for s=16ni+ln
    unsigned short h0=bfh_(p0),h1=bfh_(p1),h2=bfh_(p2v),h3=bfh_(p3v);
    unsigned short e0=bfl_(p0,h0),e1=bfl_(p1,h1),e2=bfl_(p2v,h2),e3=bfl_(p3v,h3);
    int pb=(16*ni+ln)*BSTR+16*w+4*g;
    *reinterpret_cast<uint2*>(KLh+pb)=make_uint2((unsigned)h0|((unsigned)h1<<16),(unsigned)h2|((unsigned)h3<<16));
    *reinterpret_cast<uint2*>(KLl+pb)=make_uint2((unsigned)e0|((unsigned)e1<<16),(unsigned)e2|((unsigned)e3<<16));
    den_acc[ni]+=__shfl_xor(den_acc[ni],16);   // reduce over g
    den_acc[ni]+=__shfl_xor(den_acc[ni],32);
  }
  if(lane<16){
    #pragma unroll
    for(int ni=0;ni<4;ni++) sdenw[w*64+16*ni+lane]=den_acc[ni];
  }
  __syncthreads();
  // ---- matmul2: X[s][d] = PT . P2  (A=PT s-major rows, B=P2^T d-major rows, k=m) ----
  #pragma unroll
  for(int kh=0;kh<2;kh++){
    int ab=(16*w+ln)*BSTR+32*kh+8*g;
    ah_[kh]=*reinterpret_cast<const short8*>(KLh+ab);
    al_[kh]=*reinterpret_cast<const short8*>(KLl+ab);
  }
  float inv[4];
  #pragma unroll
  for(int r=0;r<4;r++){
    int s=16*w+4*g+r;
    inv[r]=1.0f/(sdenw[s]+sdenw[64+s]+sdenw[128+s]+sdenw[192+s]);
  }
  #pragma unroll
  for(int ni=0;ni<4;ni++){
    f32x4 d=(f32x4){0.f,0.f,0.f,0.f};
    #pragma unroll
    for(int kh=0;kh<2;kh++){
      int bb=(16*ni+ln)*BSTR+32*kh+8*g;
      short8 bh=*reinterpret_cast<const short8*>(QBh+bb);
      short8 bl=*reinterpret_cast<const short8*>(QBl+bb);
      d=MFMA16(ah_[kh],bh,d); d=MFMA16(ah_[kh],bl,d); d=MFMA16(al_[kh],bh,d);
    }
    #pragma unroll
    for(int r=0;r<4;r++)
      out[((size_t)h*SEQ + (size_t)(s0+16*w+4*g+r))*DIM + 16*ni+ln] = d[r]*inv[r];
  }
}

extern "C" void kernel_launch(void* const* d_in, const int* in_sizes, int n_in,
                              void* d_out, int out_size, void* d_ws, size_t ws_size,
                              hipStream_t stream) {
  const float* Q = (const float*)d_in[0];
  const float* K = (const float*)d_in[1];
  const float* V = (const float*)d_in[2];
  float* out = (float*)d_out;
  float* ws  = (float*)d_ws;

  pool_kernel   <<<BH*32, 256, 0, stream>>>(Q, K, ws);
  k2_kernel     <<<BH,    256, 0, stream>>>(ws);
  fused_kernel  <<<BH + BH*NCHUNK, 256, 0, stream>>>(K, V, ws);
  combine_kernel<<<BH,    256, 0, stream>>>(ws);
  final_kernel  <<<BH*64, 256, 0, stream>>>(Q, out, ws);
}